// Round 4
// baseline (4428.218 us; speedup 1.0000x reference)
//
#include <hip/hip_runtime.h>

// ---------------------------------------------------------------------------
// GatedDeltaProduct: B=2,T=1024,HID=2048, NH=2, H=6, DK=256, DV=512
// Inputs are FLOAT32 (per reference dtypes); output FLOAT32.
// Internal compute: bf16 MFMA GEMMs, fp32-state sequential scan (bisect-safe).
// ---------------------------------------------------------------------------

typedef short bf16x8 __attribute__((ext_vector_type(8)));
typedef float f32x4 __attribute__((ext_vector_type(4)));

__device__ __forceinline__ float bf2f(short s) {
  unsigned u = ((unsigned)(unsigned short)s) << 16;
  float f; __builtin_memcpy(&f, &u, 4); return f;
}
__device__ __forceinline__ short f2bf(float f) {
  unsigned u; __builtin_memcpy(&u, &f, 4);
  u = (u + 0x7FFFu + ((u >> 16) & 1u)) >> 16;
  return (short)u;
}
__device__ __forceinline__ f32x4 MFMA(bf16x8 a, bf16x8 b, f32x4 c) {
  return __builtin_amdgcn_mfma_f32_16x16x32_bf16(a, b, c, 0, 0, 0);
}

#define PJ_N 13824   // [q 0:1536][k0][k1][v0 4608:][v1 7680:][gate 10752:]
#define NTOK 2048    // B*T rows

// ---------------------------------------------------------------------------
// fp32 -> bf16 bulk convert (for x). n multiple of 8.
__global__ __launch_bounds__(256) void cvt_bf16(
    const float* __restrict__ src, short* __restrict__ dst, int n)
{
  int i = (blockIdx.x * 256 + threadIdx.x) * 8;
  if (i + 8 <= n) {
    float4 a = *(const float4*)(src + i);
    float4 b = *(const float4*)(src + i + 4);
    short v[8] = {f2bf(a.x), f2bf(a.y), f2bf(a.z), f2bf(a.w),
                  f2bf(b.x), f2bf(b.y), f2bf(b.z), f2bf(b.w)};
    uint4 u; __builtin_memcpy(&u, v, 16);
    *(uint4*)(dst + i) = u;
  }
}

// ---------------------------------------------------------------------------
// Weight transpose + convert: W (K x N, fp32) -> WT (N x K, bf16).
__global__ __launch_bounds__(256) void transpose_w(
    const float* __restrict__ W, short* __restrict__ WT, int K, int N)
{
  int lane = threadIdx.x & 63, y = threadIdx.x >> 6;
  int n = blockIdx.x * 64 + lane;
  for (int k0 = y * 8; k0 < K; k0 += 32) {
    short v[8];
    #pragma unroll
    for (int j = 0; j < 8; ++j) v[j] = f2bf(W[(size_t)(k0 + j) * N + n]);
    uint4 u; __builtin_memcpy(&u, v, 16);
    *(uint4*)(WT + (size_t)n * K + k0) = u;
  }
}

// ---------------------------------------------------------------------------
// GEMM: C[M,N] = A[M,K] @ B, given BT (N x K). bf16 in, fp32 accum.
// F32OUT selects float or bf16 C. 128x128 tile, BK=64, 256 threads.
template<bool F32OUT>
__global__ __launch_bounds__(256) void gemm_bt(
    const short* __restrict__ A, const short* __restrict__ BT,
    void* __restrict__ Cp, int M, int N, int K)
{
  __shared__ short As[128 * 72];
  __shared__ short Bs[128 * 72];
  const int tid = threadIdx.x;
  const int lane = tid & 63, wv = tid >> 6;
  const int quad = lane >> 4, l16 = lane & 15;
  const int m0 = blockIdx.y * 128, n0 = blockIdx.x * 128;
  const int wm = (wv >> 1) * 64, wn = (wv & 1) * 64;
  const int srow = tid >> 1, sseg = (tid & 1) * 32;
  f32x4 zz = {0.f, 0.f, 0.f, 0.f};
  f32x4 acc[4][4];
  #pragma unroll
  for (int i = 0; i < 4; ++i)
    #pragma unroll
    for (int j = 0; j < 4; ++j) acc[i][j] = zz;
  const short* ga = A + (size_t)(m0 + srow) * K + sseg;
  const short* gb = BT + (size_t)(n0 + srow) * K + sseg;
  for (int k0 = 0; k0 < K; k0 += 64) {
    uint4 va[4], vb[4];
    #pragma unroll
    for (int e = 0; e < 4; ++e) {
      va[e] = *(const uint4*)(ga + k0 + e * 8);
      vb[e] = *(const uint4*)(gb + k0 + e * 8);
    }
    __syncthreads();
    #pragma unroll
    for (int e = 0; e < 4; ++e) {
      *(uint4*)(As + srow * 72 + sseg + e * 8) = va[e];
      *(uint4*)(Bs + srow * 72 + sseg + e * 8) = vb[e];
    }
    __syncthreads();
    #pragma unroll
    for (int kk = 0; kk < 64; kk += 32) {
      bf16x8 af[4], bfr[4];
      #pragma unroll
      for (int i = 0; i < 4; ++i)
        af[i] = *(const bf16x8*)(As + (wm + i * 16 + l16) * 72 + kk + quad * 8);
      #pragma unroll
      for (int j = 0; j < 4; ++j)
        bfr[j] = *(const bf16x8*)(Bs + (wn + j * 16 + l16) * 72 + kk + quad * 8);
      #pragma unroll
      for (int i = 0; i < 4; ++i)
        #pragma unroll
        for (int j = 0; j < 4; ++j)
          acc[i][j] = MFMA(af[i], bfr[j], acc[i][j]);
    }
  }
  #pragma unroll
  for (int i = 0; i < 4; ++i)
    #pragma unroll
    for (int j = 0; j < 4; ++j)
      #pragma unroll
      for (int r = 0; r < 4; ++r) {
        int row = m0 + wm + i * 16 + quad * 4 + r;
        int col = n0 + wn + j * 16 + l16;
        if (F32OUT) ((float*)Cp)[(size_t)row * N + col] = acc[i][j][r];
        else        ((short*)Cp)[(size_t)row * N + col] = f2bf(acc[i][j][r]);
      }
}

// ---------------------------------------------------------------------------
// beta (sigmoid(x@b_ws[i])) and g (-exp(A_log)*softplus(x@a_w+dt_bias)).
// One wave per row; all inputs fp32.
__global__ __launch_bounds__(64) void proj_small(
    const float* __restrict__ x, const float* __restrict__ b_ws,
    const float* __restrict__ a_w, const float* __restrict__ A_log,
    const float* __restrict__ dt_bias,
    float* __restrict__ Beta0, float* __restrict__ Beta1, float* __restrict__ G)
{
  int row = blockIdx.x, lane = threadIdx.x;
  float p[18];
  #pragma unroll
  for (int j = 0; j < 18; ++j) p[j] = 0.f;
  for (int k = lane; k < 2048; k += 64) {
    float xv = x[(size_t)row * 2048 + k];
    const float* b0 = b_ws + (size_t)k * 6;
    const float* b1 = b_ws + (size_t)2048 * 6 + (size_t)k * 6;
    const float* aw = a_w + (size_t)k * 6;
    #pragma unroll
    for (int j = 0; j < 6; ++j) {
      p[j]      += xv * b0[j];
      p[6 + j]  += xv * b1[j];
      p[12 + j] += xv * aw[j];
    }
  }
  #pragma unroll
  for (int j = 0; j < 18; ++j) {
    #pragma unroll
    for (int off = 32; off > 0; off >>= 1)
      p[j] += __shfl_down(p[j], off);
  }
  if (lane == 0) {
    #pragma unroll
    for (int j = 0; j < 6; ++j) {
      Beta0[(size_t)row * 6 + j] = 1.f / (1.f + expf(-p[j]));
      Beta1[(size_t)row * 6 + j] = 1.f / (1.f + expf(-p[6 + j]));
      float z = p[12 + j] + dt_bias[j];
      float sp = (z > 15.f) ? z : log1pf(expf(z));
      G[(size_t)row * 6 + j] = -expf(A_log[j]) * sp;
    }
  }
}

// ---------------------------------------------------------------------------
// Conv(K=4 causal, depthwise) + SiLU + per-head l2norm (q/k). grid (2048, 6).
__global__ __launch_bounds__(256) void conv_norm_qk(
    const short* __restrict__ P, const float* __restrict__ convw,
    short* __restrict__ dst, int colofs, float scale)
{
  __shared__ float red[256];
  int c = threadIdx.x, h = blockIdx.y, row = blockIdx.x;
  int t = row & 1023;
  int ch = colofs + h * 256 + c;
  const float* cw = convw + (size_t)(h * 256 + c) * 4;
  float acc = 0.f;
  #pragma unroll
  for (int j = 0; j < 4; ++j) {
    int tt = t - 3 + j;
    if (tt >= 0) acc += bf2f(P[(size_t)(row - 3 + j) * PJ_N + ch]) * cw[j];
  }
  float y = acc / (1.f + expf(-acc));   // silu
  red[c] = y * y;
  __syncthreads();
  for (int s = 128; s > 0; s >>= 1) {
    if (c < s) red[c] += red[c + s];
    __syncthreads();
  }
  float nrm = rsqrtf(red[0] + 1e-12f) * scale;
  dst[((size_t)row * 6 + h) * 256 + c] = f2bf(y * nrm);
}

// Conv + SiLU for v. grid (2048, 12).
__global__ __launch_bounds__(256) void conv_v(
    const short* __restrict__ P, const float* __restrict__ convw,
    short* __restrict__ dst, int colofs)
{
  int cg = blockIdx.y * 256 + threadIdx.x;
  int row = blockIdx.x;
  int t = row & 1023;
  const float* cw = convw + (size_t)cg * 4;
  float acc = 0.f;
  #pragma unroll
  for (int j = 0; j < 4; ++j) {
    int tt = t - 3 + j;
    if (tt >= 0) acc += bf2f(P[(size_t)(row - 3 + j) * PJ_N + colofs + cg]) * cw[j];
  }
  float y = acc / (1.f + expf(-acc));
  dst[(size_t)row * 3072 + cg] = f2bf(y);
}

// ---------------------------------------------------------------------------
// Sequential gated-delta scan, fp32 state in LDS. One block per
// (b, h, 32-col DV slice): grid (16, 6, 2), block 256.
// Thread (dg = tid>>5, col = tid&31) owns S[dg*32 .. +32)[col].
#define SEQLD 33
__global__ __launch_bounds__(256) void scan_seq(
    const short* __restrict__ Qc, const short* __restrict__ K0c,
    const short* __restrict__ K1c, const short* __restrict__ V0c,
    const short* __restrict__ V1c,
    const float* __restrict__ Beta0, const float* __restrict__ Beta1,
    const float* __restrict__ G, short* __restrict__ O)
{
  __shared__ float S[256 * SEQLD];   // state slice [d][vl], fp32, padded
  __shared__ float ksh[256];
  __shared__ float qsh[256];
  __shared__ float red[8 * 32];
  __shared__ float ush[32];
  int tid = threadIdx.x;
  int col = tid & 31, dg = tid >> 5;
  int vs = blockIdx.x * 32;
  int h = blockIdx.y, b = blockIdx.z;
  for (int e = tid; e < 256 * SEQLD; e += 256) S[e] = 0.f;
  __syncthreads();

  for (int i = 0; i < 1024; ++i) {
    size_t rowbase = (size_t)(b * 1024 + i) * 6 + h;
    size_t vrow = (size_t)(b * 1024 + i) * 3072 + h * 512 + vs;
    // ---------- even sub-step: decay e^g, insert (k0, v0, beta0) ----------
    float eg = expf(G[rowbase]);
    float b0 = Beta0[rowbase];
    ksh[tid] = bf2f(K0c[rowbase * 256 + tid]);
    float vv0 = (tid < 32) ? bf2f(V0c[vrow + tid]) : 0.f;
    __syncthreads();                               // B1: ksh ready
    float pk = 0.f;
    #pragma unroll
    for (int j = 0; j < 32; ++j)
      pk += ksh[dg * 32 + j] * S[(dg * 32 + j) * SEQLD + col];
    red[dg * 32 + col] = pk;
    __syncthreads();                               // B2: partials ready
    if (dg == 0) {
      float s = 0.f;
      #pragma unroll
      for (int r = 0; r < 8; ++r) s += red[r * 32 + col];
      ush[col] = b0 * (vv0 - eg * s);              // u = beta*(v - k.(e^g S))
    }
    __syncthreads();                               // B3: u ready
    float u0 = ush[col];
    #pragma unroll
    for (int j = 0; j < 32; ++j) {
      int d = dg * 32 + j;
      S[d * SEQLD + col] = eg * S[d * SEQLD + col] + ksh[d] * u0;
    }
    __syncthreads();                               // B4: S updated, ksh free
    // ---------- odd sub-step: insert (k1, v1, beta1), emit o = q.S ----------
    float b1 = Beta1[rowbase];
    ksh[tid] = bf2f(K1c[rowbase * 256 + tid]);
    qsh[tid] = bf2f(Qc[rowbase * 256 + tid]);
    float vv1 = (tid < 32) ? bf2f(V1c[vrow + tid]) : 0.f;
    __syncthreads();                               // B5: ksh/qsh ready
    float pk1 = 0.f;
    #pragma unroll
    for (int j = 0; j < 32; ++j)
      pk1 += ksh[dg * 32 + j] * S[(dg * 32 + j) * SEQLD + col];
    red[dg * 32 + col] = pk1;
    __syncthreads();                               // B6: partials ready
    if (dg == 0) {
      float s = 0.f;
      #pragma unroll
      for (int r = 0; r < 8; ++r) s += red[r * 32 + col];
      ush[col] = b1 * (vv1 - s);
    }
    __syncthreads();                               // B7: u ready
    float u1 = ush[col];
    float po = 0.f;
    #pragma unroll
    for (int j = 0; j < 32; ++j) {
      int d = dg * 32 + j;
      float sn = S[d * SEQLD + col] + ksh[d] * u1;
      S[d * SEQLD + col] = sn;
      po += qsh[d] * sn;
    }
    red[dg * 32 + col] = po;
    __syncthreads();                               // B8: o partials ready
    if (dg == 0) {
      float s = 0.f;
      #pragma unroll
      for (int r = 0; r < 8; ++r) s += red[r * 32 + col];
      O[rowbase * 512 + vs + col] = f2bf(s);
    }
    __syncthreads();                               // B9: red free for next i
  }
}

// ---------------------------------------------------------------------------
// RMS-norm over DV per (b,t,h), times silu(gate). grid (2048, 6).
__global__ __launch_bounds__(256) void rms_gate(
    const short* __restrict__ O, const short* __restrict__ P,
    const float* __restrict__ onw, short* __restrict__ OutPre)
{
  __shared__ float red[256];
  int tid = threadIdx.x, h = blockIdx.y, row = blockIdx.x;
  size_t base = ((size_t)row * 6 + h) * 512;
  float a = bf2f(O[base + tid]), b2 = bf2f(O[base + 256 + tid]);
  red[tid] = a * a + b2 * b2;
  __syncthreads();
  for (int s = 128; s > 0; s >>= 1) {
    if (tid < s) red[tid] += red[tid + s];
    __syncthreads();
  }
  float r = rsqrtf(red[0] * (1.f / 512.f) + 1e-5f);
  #pragma unroll
  for (int half = 0; half < 2; ++half) {
    int col = tid + half * 256;
    float ov = half ? b2 : a;
    float g = bf2f(P[(size_t)row * PJ_N + 10752 + h * 512 + col]);
    float sg = g / (1.f + expf(-g));
    OutPre[(size_t)row * 3072 + h * 512 + col] = f2bf(ov * r * onw[col] * sg);
  }
}

// ---------------------------------------------------------------------------
extern "C" void kernel_launch(void* const* d_in, const int* in_sizes, int n_in,
                              void* d_out, int out_size, void* d_ws, size_t ws_size,
                              hipStream_t stream) {
  const float* x        = (const float*)d_in[0];
  const float* q_w      = (const float*)d_in[1];
  const float* k_ws     = (const float*)d_in[2];
  const float* v_ws     = (const float*)d_in[3];
  const float* b_ws     = (const float*)d_in[4];
  const float* a_w      = (const float*)d_in[5];
  const float* g_w      = (const float*)d_in[6];
  const float* o_w      = (const float*)d_in[7];
  const float* q_conv_w = (const float*)d_in[8];
  const float* k_conv   = (const float*)d_in[9];
  const float* v_conv   = (const float*)d_in[10];
  const float* A_log    = (const float*)d_in[11];
  const float* dt_bias  = (const float*)d_in[12];
  const float* o_norm_w = (const float*)d_in[13];
  float* out = (float*)d_out;

  char* ws = (char*)d_ws;
  size_t off = 0;
  auto take = [&](size_t bytes) {
    size_t r = off;
    off += (bytes + 255) & ~(size_t)255;
    return r;
  };
  // Persistent buffers
  short* P  = (short*)(ws + take((size_t)NTOK * PJ_N * 2));   // live steps 3-8
  short* oT = (short*)(ws + take((size_t)2048 * 3072 * 2));   // live 2-9
  short* xbf = (short*)(ws + take((size_t)NTOK * 2048 * 2));  // bf16 copy of x
  // Region A: WTall (steps 2-3) reused for O/OutPre (steps 7-9)
  size_t regA = take((size_t)PJ_N * 2048 * 2);                // 56.6 MB
  short* WTall  = (short*)(ws + regA);
  short* O      = (short*)(ws + regA);                        // 12.6 MB
  short* OutPre = O + (size_t)NTOK * 6 * 512;                 // 12.6 MB
  // Region B: conv outputs (steps 5-7), read during scan — NOT aliased with O
  short* Qc  = (short*)(ws + take((size_t)NTOK * 1536 * 2));
  short* K0c = (short*)(ws + take((size_t)NTOK * 1536 * 2));
  short* K1c = (short*)(ws + take((size_t)NTOK * 1536 * 2));
  short* V0c = (short*)(ws + take((size_t)NTOK * 3072 * 2));
  short* V1c = (short*)(ws + take((size_t)NTOK * 3072 * 2));
  float* Beta0 = (float*)(ws + take((size_t)NTOK * 6 * 4));
  float* Beta1 = (float*)(ws + take((size_t)NTOK * 6 * 4));
  float* G     = (float*)(ws + take((size_t)NTOK * 6 * 4));
  if (off > ws_size) return;  // ws too small: no-op (diagnosable, capture-safe)

  // 1) convert x to bf16
  cvt_bf16<<<dim3(NTOK * 2048 / 8 / 256), 256, 0, stream>>>(x, xbf, NTOK * 2048);

  // 2) weight transposes (fp32 -> bf16) into WTall [q|k0|k1|v0|v1|gate] and oT
  transpose_w<<<dim3(24), 256, 0, stream>>>(q_w, WTall, 2048, 1536);
  transpose_w<<<dim3(24), 256, 0, stream>>>(k_ws, WTall + (size_t)1536 * 2048, 2048, 1536);
  transpose_w<<<dim3(24), 256, 0, stream>>>(k_ws + (size_t)2048 * 1536, WTall + (size_t)3072 * 2048, 2048, 1536);
  transpose_w<<<dim3(48), 256, 0, stream>>>(v_ws, WTall + (size_t)4608 * 2048, 2048, 3072);
  transpose_w<<<dim3(48), 256, 0, stream>>>(v_ws + (size_t)2048 * 3072, WTall + (size_t)7680 * 2048, 2048, 3072);
  transpose_w<<<dim3(48), 256, 0, stream>>>(g_w, WTall + (size_t)10752 * 2048, 2048, 3072);
  transpose_w<<<dim3(32), 256, 0, stream>>>(o_w, oT, 3072, 2048);

  // 3) fused projection GEMM: P = x @ [q_w|k0|k1|v0|v1|g_w]  (bf16 out)
  gemm_bt<false><<<dim3(PJ_N / 128, NTOK / 128), 256, 0, stream>>>(
      xbf, WTall, P, NTOK, PJ_N, 2048);

  // 4) beta / g (fp32 inputs straight from d_in)
  proj_small<<<dim3(NTOK), 64, 0, stream>>>(x, b_ws, a_w, A_log, dt_bias, Beta0, Beta1, G);

  // 5) conv + silu (+ l2norm for q/k)
  conv_norm_qk<<<dim3(NTOK, 6), 256, 0, stream>>>(P, q_conv_w, Qc, 0, 0.0625f);
  conv_norm_qk<<<dim3(NTOK, 6), 256, 0, stream>>>(P, k_conv, K0c, 1536, 1.f);
  conv_norm_qk<<<dim3(NTOK, 6), 256, 0, stream>>>(P, k_conv + (size_t)1536 * 4, K1c, 3072, 1.f);
  conv_v<<<dim3(NTOK, 12), 256, 0, stream>>>(P, v_conv, V0c, 4608);
  conv_v<<<dim3(NTOK, 12), 256, 0, stream>>>(P, v_conv + (size_t)3072 * 4, V1c, 7680);

  // 6) sequential scan (fp32 state)
  scan_seq<<<dim3(16, 6, 2), 256, 0, stream>>>(Qc, K0c, K1c, V0c, V1c,
      Beta0, Beta1, G, O);

  // 7) rms-norm * silu(gate)
  rms_gate<<<dim3(NTOK, 6), 256, 0, stream>>>(O, P, o_norm_w, OutPre);

  // 8) output projection (fp32 out)
  gemm_bt<true><<<dim3(2048 / 128, NTOK / 128), 256, 0, stream>>>(
      OutPre, oT, out, NTOK, 2048, 3072);
}

// Round 5
// 2323.783 us; speedup vs baseline: 1.9056x; 1.9056x over previous
//
#include <hip/hip_runtime.h>

// ---------------------------------------------------------------------------
// GatedDeltaProduct: B=2,T=1024,HID=2048, NH=2, H=6, DK=256, DV=512, CHUNK=64
// Inputs fp32, output fp32. Internal bf16 MFMA. WY chunked gated delta rule:
// 384 independent scan waves, 32 sequential chunk steps each.
// ---------------------------------------------------------------------------

typedef short bf16x8 __attribute__((ext_vector_type(8)));
typedef float f32x4 __attribute__((ext_vector_type(4)));

__device__ __forceinline__ float bf2f(short s) {
  unsigned u = ((unsigned)(unsigned short)s) << 16;
  float f; __builtin_memcpy(&f, &u, 4); return f;
}
__device__ __forceinline__ short f2bf(float f) {
  unsigned u; __builtin_memcpy(&u, &f, 4);
  u = (u + 0x7FFFu + ((u >> 16) & 1u)) >> 16;
  return (short)u;
}
__device__ __forceinline__ f32x4 MFMA(bf16x8 a, bf16x8 b, f32x4 c) {
  return __builtin_amdgcn_mfma_f32_16x16x32_bf16(a, b, c, 0, 0, 0);
}

#define PJ_N 13824   // [q 0:1536][k0][k1][v0 4608:][v1 7680:][gate 10752:]
#define NTOK 2048    // B*T rows

// ---------------------------------------------------------------------------
// fp32 -> bf16 bulk convert (for x). n multiple of 8.
__global__ __launch_bounds__(256) void cvt_bf16(
    const float* __restrict__ src, short* __restrict__ dst, int n)
{
  int i = (blockIdx.x * 256 + threadIdx.x) * 8;
  if (i + 8 <= n) {
    float4 a = *(const float4*)(src + i);
    float4 b = *(const float4*)(src + i + 4);
    short v[8] = {f2bf(a.x), f2bf(a.y), f2bf(a.z), f2bf(a.w),
                  f2bf(b.x), f2bf(b.y), f2bf(b.z), f2bf(b.w)};
    uint4 u; __builtin_memcpy(&u, v, 16);
    *(uint4*)(dst + i) = u;
  }
}

// ---------------------------------------------------------------------------
// Weight transpose + convert: W (K x N, fp32) -> WT (N x K, bf16).
__global__ __launch_bounds__(256) void transpose_w(
    const float* __restrict__ W, short* __restrict__ WT, int K, int N)
{
  int lane = threadIdx.x & 63, y = threadIdx.x >> 6;
  int n = blockIdx.x * 64 + lane;
  for (int k0 = y * 8; k0 < K; k0 += 32) {
    short v[8];
    #pragma unroll
    for (int j = 0; j < 8; ++j) v[j] = f2bf(W[(size_t)(k0 + j) * N + n]);
    uint4 u; __builtin_memcpy(&u, v, 16);
    *(uint4*)(WT + (size_t)n * K + k0) = u;
  }
}

// ---------------------------------------------------------------------------
// GEMM: C[M,N] = A[M,K] @ B, given BT (N x K). bf16 in, fp32 accum.
template<bool F32OUT>
__global__ __launch_bounds__(256) void gemm_bt(
    const short* __restrict__ A, const short* __restrict__ BT,
    void* __restrict__ Cp, int M, int N, int K)
{
  __shared__ short As[128 * 72];
  __shared__ short Bs[128 * 72];
  const int tid = threadIdx.x;
  const int lane = tid & 63, wv = tid >> 6;
  const int quad = lane >> 4, l16 = lane & 15;
  const int m0 = blockIdx.y * 128, n0 = blockIdx.x * 128;
  const int wm = (wv >> 1) * 64, wn = (wv & 1) * 64;
  const int srow = tid >> 1, sseg = (tid & 1) * 32;
  f32x4 zz = {0.f, 0.f, 0.f, 0.f};
  f32x4 acc[4][4];
  #pragma unroll
  for (int i = 0; i < 4; ++i)
    #pragma unroll
    for (int j = 0; j < 4; ++j) acc[i][j] = zz;
  const short* ga = A + (size_t)(m0 + srow) * K + sseg;
  const short* gb = BT + (size_t)(n0 + srow) * K + sseg;
  for (int k0 = 0; k0 < K; k0 += 64) {
    uint4 va[4], vb[4];
    #pragma unroll
    for (int e = 0; e < 4; ++e) {
      va[e] = *(const uint4*)(ga + k0 + e * 8);
      vb[e] = *(const uint4*)(gb + k0 + e * 8);
    }
    __syncthreads();
    #pragma unroll
    for (int e = 0; e < 4; ++e) {
      *(uint4*)(As + srow * 72 + sseg + e * 8) = va[e];
      *(uint4*)(Bs + srow * 72 + sseg + e * 8) = vb[e];
    }
    __syncthreads();
    #pragma unroll
    for (int kk = 0; kk < 64; kk += 32) {
      bf16x8 af[4], bfr[4];
      #pragma unroll
      for (int i = 0; i < 4; ++i)
        af[i] = *(const bf16x8*)(As + (wm + i * 16 + l16) * 72 + kk + quad * 8);
      #pragma unroll
      for (int j = 0; j < 4; ++j)
        bfr[j] = *(const bf16x8*)(Bs + (wn + j * 16 + l16) * 72 + kk + quad * 8);
      #pragma unroll
      for (int i = 0; i < 4; ++i)
        #pragma unroll
        for (int j = 0; j < 4; ++j)
          acc[i][j] = MFMA(af[i], bfr[j], acc[i][j]);
    }
  }
  #pragma unroll
  for (int i = 0; i < 4; ++i)
    #pragma unroll
    for (int j = 0; j < 4; ++j)
      #pragma unroll
      for (int r = 0; r < 4; ++r) {
        int row = m0 + wm + i * 16 + quad * 4 + r;
        int col = n0 + wn + j * 16 + l16;
        if (F32OUT) ((float*)Cp)[(size_t)row * N + col] = acc[i][j][r];
        else        ((short*)Cp)[(size_t)row * N + col] = f2bf(acc[i][j][r]);
      }
}

// ---------------------------------------------------------------------------
// beta (sigmoid(x@b_ws[i])) and g (-exp(A_log)*softplus(x@a_w+dt_bias)).
__global__ __launch_bounds__(64) void proj_small(
    const float* __restrict__ x, const float* __restrict__ b_ws,
    const float* __restrict__ a_w, const float* __restrict__ A_log,
    const float* __restrict__ dt_bias,
    float* __restrict__ Beta0, float* __restrict__ Beta1, float* __restrict__ G)
{
  int row = blockIdx.x, lane = threadIdx.x;
  float p[18];
  #pragma unroll
  for (int j = 0; j < 18; ++j) p[j] = 0.f;
  for (int k = lane; k < 2048; k += 64) {
    float xv = x[(size_t)row * 2048 + k];
    const float* b0 = b_ws + (size_t)k * 6;
    const float* b1 = b_ws + (size_t)2048 * 6 + (size_t)k * 6;
    const float* aw = a_w + (size_t)k * 6;
    #pragma unroll
    for (int j = 0; j < 6; ++j) {
      p[j]      += xv * b0[j];
      p[6 + j]  += xv * b1[j];
      p[12 + j] += xv * aw[j];
    }
  }
  #pragma unroll
  for (int j = 0; j < 18; ++j) {
    #pragma unroll
    for (int off = 32; off > 0; off >>= 1)
      p[j] += __shfl_down(p[j], off);
  }
  if (lane == 0) {
    #pragma unroll
    for (int j = 0; j < 6; ++j) {
      Beta0[(size_t)row * 6 + j] = 1.f / (1.f + expf(-p[j]));
      Beta1[(size_t)row * 6 + j] = 1.f / (1.f + expf(-p[6 + j]));
      float z = p[12 + j] + dt_bias[j];
      float sp = (z > 15.f) ? z : log1pf(expf(z));
      G[(size_t)row * 6 + j] = -expf(A_log[j]) * sp;
    }
  }
}

// ---------------------------------------------------------------------------
// Conv(K=4 causal, depthwise) + SiLU + per-head l2norm (q/k). grid (2048, 6).
__global__ __launch_bounds__(256) void conv_norm_qk(
    const short* __restrict__ P, const float* __restrict__ convw,
    short* __restrict__ dst, int colofs, float scale)
{
  __shared__ float red[256];
  int c = threadIdx.x, h = blockIdx.y, row = blockIdx.x;
  int t = row & 1023;
  int ch = colofs + h * 256 + c;
  const float* cw = convw + (size_t)(h * 256 + c) * 4;
  float acc = 0.f;
  #pragma unroll
  for (int j = 0; j < 4; ++j) {
    int tt = t - 3 + j;
    if (tt >= 0) acc += bf2f(P[(size_t)(row - 3 + j) * PJ_N + ch]) * cw[j];
  }
  float y = acc / (1.f + expf(-acc));   // silu
  red[c] = y * y;
  __syncthreads();
  for (int s = 128; s > 0; s >>= 1) {
    if (c < s) red[c] += red[c + s];
    __syncthreads();
  }
  float nrm = rsqrtf(red[0] + 1e-12f) * scale;
  dst[((size_t)row * 6 + h) * 256 + c] = f2bf(y * nrm);
}

// Conv + SiLU for v. grid (2048, 12).
__global__ __launch_bounds__(256) void conv_v(
    const short* __restrict__ P, const float* __restrict__ convw,
    short* __restrict__ dst, int colofs)
{
  int cg = blockIdx.y * 256 + threadIdx.x;
  int row = blockIdx.x;
  int t = row & 1023;
  const float* cw = convw + (size_t)cg * 4;
  float acc = 0.f;
  #pragma unroll
  for (int j = 0; j < 4; ++j) {
    int tt = t - 3 + j;
    if (tt >= 0) acc += bf2f(P[(size_t)(row - 3 + j) * PJ_N + colofs + cg]) * cw[j];
  }
  float y = acc / (1.f + expf(-acc));
  dst[(size_t)row * 3072 + cg] = f2bf(y);
}

// ---------------------------------------------------------------------------
// Per-(b,h,chunk) precompute of WY operands. grid (32, 6, 2), block 256.
// Qg/Mm store only odd interleaved rows (32 per chunk).
#define KBLD 264
#define R2LD 72
#define WTLD 72
__global__ __launch_bounds__(256) void precompute_chunk(
    const short* __restrict__ Qc, const short* __restrict__ K0c, const short* __restrict__ K1c,
    const short* __restrict__ V0c, const short* __restrict__ V1c,
    const float* __restrict__ Beta0, const float* __restrict__ Beta1, const float* __restrict__ G,
    short* __restrict__ NTW, short* __restrict__ Qg, short* __restrict__ KdT,
    short* __restrict__ Mm, short* __restrict__ TBV, float* __restrict__ dC)
{
  __shared__ short r0[256 * 72];   // kb (64 x KBLD) -> wt (256 x WTLD) -> BVT
  __shared__ float Xs[64 * 64];    // (I+A)^-1 (f32)
  __shared__ short r2[64 * 72];    // KK^T (bf16) -> X (bf16)
  const int tid = threadIdx.x;
  const int lane = tid & 63, wv = tid >> 6;
  const int quad = lane >> 4, l16 = lane & 15;
  const int c = blockIdx.x, h = blockIdx.y, b = blockIdx.z;
  const int i0 = c * 32;
  const size_t idx = (size_t)((b * 6 + h) * 32 + c);
  short* kb = r0;
  f32x4 zz = {0.f, 0.f, 0.f, 0.f};
  bf16x8 z8 = {0, 0, 0, 0, 0, 0, 0, 0};

  // per-lane g/beta for interleaved position t = lane; wave-prefix cumsum
  float gv, betaL;
  {
    int t = lane, par = t & 1, i = i0 + (t >> 1);
    size_t gofs = (size_t)(b * 1024 + i) * 6 + h;
    gv = par ? 0.f : G[gofs];
    betaL = par ? Beta1[gofs] : Beta0[gofs];
  }
  float cum = gv;
  #pragma unroll
  for (int off = 1; off < 64; off <<= 1) {
    float nb = __shfl_up(cum, off);
    if (lane >= off) cum += nb;
  }
  float c63 = __shfl(cum, 63);
  float eBt = expf(cum);          // exp(B_t)
  float eRem = expf(c63 - cum);   // exp(B63 - B_t)
  float wsc = betaL * eBt;        // beta_t exp(B_t)
  if (tid == 0) dC[idx] = expf(c63);

  // stage k chunk (interleaved parities) into kb
  {
    int row = tid >> 2, seg = (tid & 3) * 64;
    int par = row & 1, i = i0 + (row >> 1);
    const short* src = (par ? K1c : K0c) + ((size_t)(b * 1024 + i) * 6 + h) * 256 + seg;
    short* dp = kb + row * KBLD + seg;
    #pragma unroll
    for (int e = 0; e < 64; e += 8)
      *(uint4*)(dp + e) = *(const uint4*)(src + e);
  }
  __syncthreads();

  // KK^T (bf16 into r2). wave = t row-tile.
  {
    f32x4 acc[4];
    #pragma unroll
    for (int ts = 0; ts < 4; ++ts) acc[ts] = zz;
    #pragma unroll
    for (int ks = 0; ks < 8; ++ks) {
      bf16x8 af = *(const bf16x8*)(kb + (wv * 16 + l16) * KBLD + ks * 32 + quad * 8);
      #pragma unroll
      for (int ts = 0; ts < 4; ++ts) {
        bf16x8 bfv = *(const bf16x8*)(kb + (ts * 16 + l16) * KBLD + ks * 32 + quad * 8);
        acc[ts] = MFMA(af, bfv, acc[ts]);
      }
    }
    #pragma unroll
    for (int ts = 0; ts < 4; ++ts)
      #pragma unroll
      for (int r = 0; r < 4; ++r)
        r2[(wv * 16 + quad * 4 + r) * R2LD + ts * 16 + l16] = f2bf(acc[ts][r]);
  }
  // QK^T -> M (masked, decayed; odd rows only) directly to global
  {
    f32x4 acc[4];
    #pragma unroll
    for (int ts = 0; ts < 4; ++ts) acc[ts] = zz;
    int t_row = wv * 16 + l16;
    int podd = t_row & 1, iq = i0 + (t_row >> 1);
    const short* qrow = Qc + ((size_t)(b * 1024 + iq) * 6 + h) * 256;
    #pragma unroll
    for (int ks = 0; ks < 8; ++ks) {
      bf16x8 af = z8;
      if (podd) af = *(const bf16x8*)(qrow + ks * 32 + quad * 8);
      #pragma unroll
      for (int ts = 0; ts < 4; ++ts) {
        bf16x8 bfv = *(const bf16x8*)(kb + (ts * 16 + l16) * KBLD + ks * 32 + quad * 8);
        acc[ts] = MFMA(af, bfv, acc[ts]);
      }
    }
    short* Mp = Mm + idx * 2048;
    #pragma unroll
    for (int ts = 0; ts < 4; ++ts)
      #pragma unroll
      for (int r = 1; r < 4; r += 2) {       // odd rows only
        int t = wv * 16 + quad * 4 + r, s = ts * 16 + l16;
        float ct = __shfl(cum, t), cs = __shfl(cum, s);
        float v = (s <= t) ? acc[ts][r] * expf(ct - cs) : 0.f;
        Mp[(t >> 1) * 64 + s] = f2bf(v);
      }
  }
  // Qg (odd rows only): Qg[th][d] = exp(B_{2th+1}) q_{2th+1}[d]
  {
    int th = tid >> 3, dseg = (tid & 7) * 32;
    int t = th * 2 + 1;
    float sc = __shfl(eBt, t);
    const short* qrow = Qc + ((size_t)(b * 1024 + i0 + th) * 6 + h) * 256 + dseg;
    short* qgp = Qg + idx * 8192 + (size_t)th * 256 + dseg;
    #pragma unroll
    for (int e = 0; e < 32; e += 8) {
      bf16x8 v = *(const bf16x8*)(qrow + e);
      bf16x8 w;
      #pragma unroll
      for (int q2 = 0; q2 < 8; ++q2) w[q2] = f2bf(bf2f(v[q2]) * sc);
      *(bf16x8*)(qgp + e) = w;
    }
  }
  // KdT[d][t] = exp(B63-B_t) k_t[d]
  {
    int d = tid;
    short buf[64];
    #pragma unroll
    for (int t = 0; t < 64; ++t) {
      float sc = __shfl(eRem, t);
      buf[t] = f2bf(bf2f(kb[t * KBLD + d]) * sc);
    }
    short* kp = KdT + idx * 16384 + (size_t)d * 64;
    #pragma unroll
    for (int e = 0; e < 64; e += 8) {
      uint4 v; __builtin_memcpy(&v, buf + e, 16);
      *(uint4*)(kp + e) = v;
    }
  }
  __syncthreads();

  // C1: cache kb column d = tid in registers
  short colv[64];
  {
    int d = tid;
    #pragma unroll
    for (int t = 0; t < 64; ++t) colv[t] = kb[t * KBLD + d];
  }
  __syncthreads();
  // C2: wt[d][s] = beta_s exp(B_s) k_s[d] (over r0)
  {
    int d = tid;
    short wrow[64];
    #pragma unroll
    for (int s = 0; s < 64; ++s) wrow[s] = f2bf(bf2f(colv[s]) * __shfl(wsc, s));
    short* wp = r0 + d * WTLD;
    #pragma unroll
    for (int e = 0; e < 64; e += 8) {
      uint4 v; __builtin_memcpy(&v, wrow + e, 16);
      *(uint4*)(wp + e) = v;
    }
  }
  // C3: wave0 solves X = (I+A)^-1 by forward substitution (cols = lanes)
  if (wv == 0) {
    int j = lane;
    for (int t = 0; t < 64; ++t) {
      float bt = __shfl(betaL, t);
      float ct = __shfl(cum, t);
      float sacc = 0.f;
      for (int s = 0; s < t; ++s) {
        float cs = __shfl(cum, s);
        float a = bt * expf(ct - cs) * bf2f(r2[t * R2LD + s]);
        sacc += a * Xs[s * 64 + j];
      }
      Xs[t * 64 + j] = ((t == j) ? 1.f : 0.f) - sacc;
    }
  }
  __syncthreads();
  // X -> r2 (bf16)
  for (int e = tid; e < 4096; e += 256) {
    int t = e >> 6, s = e & 63;
    r2[t * R2LD + s] = f2bf(Xs[e]);
  }
  __syncthreads();
  // NTW = -(X @ W)
  {
    f32x4 acc[4][4];
    #pragma unroll
    for (int i = 0; i < 4; ++i)
      #pragma unroll
      for (int j = 0; j < 4; ++j) acc[i][j] = zz;
    #pragma unroll
    for (int ks = 0; ks < 2; ++ks) {
      bf16x8 af[4], bfv[4];
      #pragma unroll
      for (int tt = 0; tt < 4; ++tt)
        af[tt] = *(const bf16x8*)(r2 + (tt * 16 + l16) * R2LD + ks * 32 + quad * 8);
      #pragma unroll
      for (int dt = 0; dt < 4; ++dt)
        bfv[dt] = *(const bf16x8*)(r0 + ((wv * 4 + dt) * 16 + l16) * WTLD + ks * 32 + quad * 8);
      #pragma unroll
      for (int tt = 0; tt < 4; ++tt)
        #pragma unroll
        for (int dt = 0; dt < 4; ++dt)
          acc[tt][dt] = MFMA(af[tt], bfv[dt], acc[tt][dt]);
    }
    short* np = NTW + idx * 16384;
    #pragma unroll
    for (int tt = 0; tt < 4; ++tt)
      #pragma unroll
      for (int dt = 0; dt < 4; ++dt)
        #pragma unroll
        for (int r = 0; r < 4; ++r) {
          int t = tt * 16 + quad * 4 + r, d = (wv * 4 + dt) * 16 + l16;
          np[t * 256 + d] = f2bf(-acc[tt][dt][r]);
        }
  }
  __syncthreads();
  // TBV = X @ (beta*v), two DV halves through r0
  for (int vh = 0; vh < 2; ++vh) {
    {
      int vl = tid;
      short bv[64];
      #pragma unroll
      for (int t = 0; t < 64; ++t) {
        int par = t & 1, i = i0 + (t >> 1);
        const short* src = (par ? V1c : V0c) + (size_t)(b * 1024 + i) * 3072 + h * 512 + vh * 256 + vl;
        bv[t] = f2bf(bf2f(*src) * __shfl(betaL, t));
      }
      short* bp = r0 + vl * WTLD;
      #pragma unroll
      for (int e = 0; e < 64; e += 8) {
        uint4 v; __builtin_memcpy(&v, bv + e, 16);
        *(uint4*)(bp + e) = v;
      }
    }
    __syncthreads();
    {
      f32x4 acc[4][4];
      #pragma unroll
      for (int i = 0; i < 4; ++i)
        #pragma unroll
        for (int j = 0; j < 4; ++j) acc[i][j] = zz;
      #pragma unroll
      for (int ks = 0; ks < 2; ++ks) {
        bf16x8 af[4], bfv[4];
        #pragma unroll
        for (int tt = 0; tt < 4; ++tt)
          af[tt] = *(const bf16x8*)(r2 + (tt * 16 + l16) * R2LD + ks * 32 + quad * 8);
        #pragma unroll
        for (int vt = 0; vt < 4; ++vt)
          bfv[vt] = *(const bf16x8*)(r0 + ((wv * 4 + vt) * 16 + l16) * WTLD + ks * 32 + quad * 8);
        #pragma unroll
        for (int tt = 0; tt < 4; ++tt)
          #pragma unroll
          for (int vt = 0; vt < 4; ++vt)
            acc[tt][vt] = MFMA(af[tt], bfv[vt], acc[tt][vt]);
      }
      short* tp = TBV + idx * 32768;
      #pragma unroll
      for (int tt = 0; tt < 4; ++tt)
        #pragma unroll
        for (int vt = 0; vt < 4; ++vt)
          #pragma unroll
          for (int r = 0; r < 4; ++r) {
            int t = tt * 16 + quad * 4 + r, v = (wv * 4 + vt) * 16 + l16;
            tp[t * 512 + vh * 256 + v] = f2bf(acc[tt][vt][r]);
          }
    }
    __syncthreads();
  }
}

// ---------------------------------------------------------------------------
// Scan: one wave per (b,h,16-col slice of DV). grid 384, block 64.
#define SLD 264
#define ULD 72
__global__ __launch_bounds__(64) void scan_kernel(
    const short* __restrict__ NTW, const short* __restrict__ Qg,
    const short* __restrict__ KdT, const short* __restrict__ Mm,
    const short* __restrict__ TBV, const float* __restrict__ dC,
    short* __restrict__ O)
{
  __shared__ short S[16 * SLD];   // state slice, [v_local][d], bf16
  __shared__ short U[16 * ULD];   // u slice, [v_local][t], bf16
  int lane = threadIdx.x;
  int quad = lane >> 4, l16 = lane & 15;
  int bh = blockIdx.x >> 5, slice = blockIdx.x & 31;
  int b = bh / 6, h = bh % 6;
  int vbase = slice * 16;
  f32x4 zz = {0.f, 0.f, 0.f, 0.f};
  for (int e = lane; e < 16 * SLD; e += 64) S[e] = 0;
  __syncthreads();

  for (int c = 0; c < 32; ++c) {
    size_t idx = (size_t)(bh * 32 + c);
    const short* ntw = NTW + idx * 16384;
    const short* qg  = Qg  + idx * 8192;
    const short* kdt = KdT + idx * 16384;
    const short* mp  = Mm  + idx * 2048;
    const short* tb  = TBV + idx * 32768;
    float dc = dC[idx];

    // u = NTW @ S0 + TBV
    f32x4 uac[4];
    #pragma unroll
    for (int tt = 0; tt < 4; ++tt)
      #pragma unroll
      for (int r = 0; r < 4; ++r)
        uac[tt][r] = bf2f(tb[(size_t)(tt * 16 + quad * 4 + r) * 512 + vbase + l16]);
    #pragma unroll
    for (int ks = 0; ks < 8; ++ks) {
      bf16x8 bfv = *(const bf16x8*)(S + l16 * SLD + ks * 32 + quad * 8);
      #pragma unroll
      for (int tt = 0; tt < 4; ++tt) {
        bf16x8 af = *(const bf16x8*)(ntw + (tt * 16 + l16) * 256 + ks * 32 + quad * 8);
        uac[tt] = MFMA(af, bfv, uac[tt]);
      }
    }
    #pragma unroll
    for (int tt = 0; tt < 4; ++tt)
      #pragma unroll
      for (int r = 0; r < 4; ++r)
        U[l16 * ULD + tt * 16 + quad * 4 + r] = f2bf(uac[tt][r]);
    __syncthreads();

    // o = Qg @ S0 + M @ u   (odd interleaved rows, 32 of them)
    f32x4 oac[2];
    #pragma unroll
    for (int tt = 0; tt < 2; ++tt) oac[tt] = zz;
    #pragma unroll
    for (int ks = 0; ks < 8; ++ks) {
      bf16x8 bfv = *(const bf16x8*)(S + l16 * SLD + ks * 32 + quad * 8);
      #pragma unroll
      for (int tt = 0; tt < 2; ++tt) {
        bf16x8 af = *(const bf16x8*)(qg + (tt * 16 + l16) * 256 + ks * 32 + quad * 8);
        oac[tt] = MFMA(af, bfv, oac[tt]);
      }
    }
    #pragma unroll
    for (int ks = 0; ks < 2; ++ks) {
      bf16x8 bfv = *(const bf16x8*)(U + l16 * ULD + ks * 32 + quad * 8);
      #pragma unroll
      for (int tt = 0; tt < 2; ++tt) {
        bf16x8 af = *(const bf16x8*)(mp + (tt * 16 + l16) * 64 + ks * 32 + quad * 8);
        oac[tt] = MFMA(af, bfv, oac[tt]);
      }
    }
    #pragma unroll
    for (int tt = 0; tt < 2; ++tt) {
      #pragma unroll
      for (int r = 0; r < 4; ++r) {
        int th = tt * 16 + quad * 4 + r;
        int i = c * 32 + th;
        O[((size_t)(b * 1024 + i) * 6 + h) * 512 + vbase + l16] = f2bf(oac[tt][r]);
      }
    }
    __syncthreads();

    // S1 = dc * S0 + KdT @ u
    #pragma unroll
    for (int g2 = 0; g2 < 4; ++g2) {
      f32x4 sac[4];
      #pragma unroll
      for (int dt = 0; dt < 4; ++dt)
        #pragma unroll
        for (int r = 0; r < 4; ++r)
          sac[dt][r] = dc * bf2f(S[l16 * SLD + (g2 * 4 + dt) * 16 + quad * 4 + r]);
      #pragma unroll
      for (int ks = 0; ks < 2; ++ks) {
        bf16x8 bfv = *(const bf16x8*)(U + l16 * ULD + ks * 32 + quad * 8);
        #pragma unroll
        for (int dt = 0; dt < 4; ++dt) {
          bf16x8 af = *(const bf16x8*)(kdt + ((g2 * 4 + dt) * 16 + l16) * 64 + ks * 32 + quad * 8);
          sac[dt] = MFMA(af, bfv, sac[dt]);
        }
      }
      #pragma unroll
      for (int dt = 0; dt < 4; ++dt)
        #pragma unroll
        for (int r = 0; r < 4; ++r)
          S[l16 * SLD + (g2 * 4 + dt) * 16 + quad * 4 + r] = f2bf(sac[dt][r]);
    }
    __syncthreads();
  }
}

// ---------------------------------------------------------------------------
// RMS-norm over DV per (b,t,h), times silu(gate). grid (2048, 6).
__global__ __launch_bounds__(256) void rms_gate(
    const short* __restrict__ O, const short* __restrict__ P,
    const float* __restrict__ onw, short* __restrict__ OutPre)
{
  __shared__ float red[256];
  int tid = threadIdx.x, h = blockIdx.y, row = blockIdx.x;
  size_t base = ((size_t)row * 6 + h) * 512;
  float a = bf2f(O[base + tid]), b2 = bf2f(O[base + 256 + tid]);
  red[tid] = a * a + b2 * b2;
  __syncthreads();
  for (int s = 128; s > 0; s >>= 1) {
    if (tid < s) red[tid] += red[tid + s];
    __syncthreads();
  }
  float r = rsqrtf(red[0] * (1.f / 512.f) + 1e-5f);
  #pragma unroll
  for (int half = 0; half < 2; ++half) {
    int col = tid + half * 256;
    float ov = half ? b2 : a;
    float g = bf2f(P[(size_t)row * PJ_N + 10752 + h * 512 + col]);
    float sg = g / (1.f + expf(-g));
    OutPre[(size_t)row * 3072 + h * 512 + col] = f2bf(ov * r * onw[col] * sg);
  }
}

// ---------------------------------------------------------------------------
extern "C" void kernel_launch(void* const* d_in, const int* in_sizes, int n_in,
                              void* d_out, int out_size, void* d_ws, size_t ws_size,
                              hipStream_t stream) {
  const float* x        = (const float*)d_in[0];
  const float* q_w      = (const float*)d_in[1];
  const float* k_ws     = (const float*)d_in[2];
  const float* v_ws     = (const float*)d_in[3];
  const float* b_ws     = (const float*)d_in[4];
  const float* a_w      = (const float*)d_in[5];
  const float* g_w      = (const float*)d_in[6];
  const float* o_w      = (const float*)d_in[7];
  const float* q_conv_w = (const float*)d_in[8];
  const float* k_conv   = (const float*)d_in[9];
  const float* v_conv   = (const float*)d_in[10];
  const float* A_log    = (const float*)d_in[11];
  const float* dt_bias  = (const float*)d_in[12];
  const float* o_norm_w = (const float*)d_in[13];
  float* out = (float*)d_out;

  char* ws = (char*)d_ws;
  size_t off = 0;
  auto take = [&](size_t bytes) {
    size_t r = off;
    off += (bytes + 255) & ~(size_t)255;
    return r;
  };
  // Persistent buffers
  short* P  = (short*)(ws + take((size_t)NTOK * PJ_N * 2));   // live 3-8
  short* oT = (short*)(ws + take((size_t)2048 * 3072 * 2));   // live 2-9
  // xbf (step 3 only) reused for Mm (steps 6-7)
  size_t regX = take((size_t)NTOK * 2048 * 2);                // 8.39 MB
  short* xbf = (short*)(ws + regX);
  short* Mm  = (short*)(ws + regX);                           // 1.57 MB
  // Region A: WTall (steps 2-3) reused for NTW|Qg|KdT|TBV (steps 6-7)
  size_t regA = take((size_t)PJ_N * 2048 * 2);                // 56,623,104 B
  short* WTall = (short*)(ws + regA);
  short* NTW = (short*)(ws + regA);
  short* Qg  = NTW + (size_t)384 * 16384;
  short* KdT = Qg  + (size_t)384 * 8192;
  short* TBV = KdT + (size_t)384 * 16384;   // ends exactly at regA + 56,623,104
  // Region B: conv outputs (steps 5-6) reused for O/OutPre (steps 7-9)
  size_t regB = take((size_t)44040192);                       // 44.0 MB
  short* Qc  = (short*)(ws + regB);
  short* K0c = Qc  + (size_t)NTOK * 1536;
  short* K1c = K0c + (size_t)NTOK * 1536;
  short* V0c = K1c + (size_t)NTOK * 1536;
  short* V1c = V0c + (size_t)NTOK * 3072;
  short* O      = (short*)(ws + regB);                        // 12.6 MB
  short* OutPre = O + (size_t)NTOK * 6 * 512;                 // 12.6 MB
  float* Beta0 = (float*)(ws + take((size_t)NTOK * 6 * 4));
  float* Beta1 = (float*)(ws + take((size_t)NTOK * 6 * 4));
  float* G     = (float*)(ws + take((size_t)NTOK * 6 * 4));
  float* dCp   = (float*)(ws + take((size_t)384 * 4));
  if (off > ws_size) return;  // ws too small: no-op (diagnosable, capture-safe)

  // 1) convert x to bf16
  cvt_bf16<<<dim3(NTOK * 2048 / 8 / 256), 256, 0, stream>>>(x, xbf, NTOK * 2048);

  // 2) weight transposes (fp32 -> bf16) into WTall [q|k0|k1|v0|v1|gate] and oT
  transpose_w<<<dim3(24), 256, 0, stream>>>(q_w, WTall, 2048, 1536);
  transpose_w<<<dim3(24), 256, 0, stream>>>(k_ws, WTall + (size_t)1536 * 2048, 2048, 1536);
  transpose_w<<<dim3(24), 256, 0, stream>>>(k_ws + (size_t)2048 * 1536, WTall + (size_t)3072 * 2048, 2048, 1536);
  transpose_w<<<dim3(48), 256, 0, stream>>>(v_ws, WTall + (size_t)4608 * 2048, 2048, 3072);
  transpose_w<<<dim3(48), 256, 0, stream>>>(v_ws + (size_t)2048 * 3072, WTall + (size_t)7680 * 2048, 2048, 3072);
  transpose_w<<<dim3(48), 256, 0, stream>>>(g_w, WTall + (size_t)10752 * 2048, 2048, 3072);
  transpose_w<<<dim3(32), 256, 0, stream>>>(o_w, oT, 3072, 2048);

  // 3) fused projection GEMM: P = x @ [q_w|k0|k1|v0|v1|g_w]  (bf16 out)
  gemm_bt<false><<<dim3(PJ_N / 128, NTOK / 128), 256, 0, stream>>>(
      xbf, WTall, P, NTOK, PJ_N, 2048);

  // 4) beta / g (fp32 inputs straight from d_in)
  proj_small<<<dim3(NTOK), 64, 0, stream>>>(x, b_ws, a_w, A_log, dt_bias, Beta0, Beta1, G);

  // 5) conv + silu (+ l2norm for q/k)
  conv_norm_qk<<<dim3(NTOK, 6), 256, 0, stream>>>(P, q_conv_w, Qc, 0, 0.0625f);
  conv_norm_qk<<<dim3(NTOK, 6), 256, 0, stream>>>(P, k_conv, K0c, 1536, 1.f);
  conv_norm_qk<<<dim3(NTOK, 6), 256, 0, stream>>>(P, k_conv + (size_t)1536 * 4, K1c, 3072, 1.f);
  conv_v<<<dim3(NTOK, 12), 256, 0, stream>>>(P, v_conv, V0c, 4608);
  conv_v<<<dim3(NTOK, 12), 256, 0, stream>>>(P, v_conv + (size_t)3072 * 4, V1c, 7680);

  // 6) chunk operand precompute (WY form)
  precompute_chunk<<<dim3(32, 6, 2), 256, 0, stream>>>(Qc, K0c, K1c, V0c, V1c,
      Beta0, Beta1, G, NTW, Qg, KdT, Mm, TBV, dCp);

  // 7) sequential chunk scan (384 independent waves)
  scan_kernel<<<dim3(384), 64, 0, stream>>>(NTW, Qg, KdT, Mm, TBV, dCp, O);

  // 8) rms-norm * silu(gate)
  rms_gate<<<dim3(NTOK, 6), 256, 0, stream>>>(O, P, o_norm_w, OutPre);

  // 9) output projection (fp32 out)
  gemm_bt<true><<<dim3(2048 / 128, NTOK / 128), 256, 0, stream>>>(
      OutPre, oT, out, NTOK, 2048, 3072);
}

// Round 6
// 2314.716 us; speedup vs baseline: 1.9131x; 1.0039x over previous
//
#include <hip/hip_runtime.h>

// ---------------------------------------------------------------------------
// GatedDeltaProduct: B=2,T=1024,HID=2048, NH=2, H=6, DK=256, DV=512, CHUNK=64
// Inputs fp32, output fp32. Internal bf16 MFMA. WY chunked gated delta rule.
// R6: col-major GEMM block swizzle (M fastest) to kill B-tile HBM re-fetch.
// ---------------------------------------------------------------------------

typedef short bf16x8 __attribute__((ext_vector_type(8)));
typedef float f32x4 __attribute__((ext_vector_type(4)));

__device__ __forceinline__ float bf2f(short s) {
  unsigned u = ((unsigned)(unsigned short)s) << 16;
  float f; __builtin_memcpy(&f, &u, 4); return f;
}
__device__ __forceinline__ short f2bf(float f) {
  unsigned u; __builtin_memcpy(&u, &f, 4);
  u = (u + 0x7FFFu + ((u >> 16) & 1u)) >> 16;
  return (short)u;
}
__device__ __forceinline__ f32x4 MFMA(bf16x8 a, bf16x8 b, f32x4 c) {
  return __builtin_amdgcn_mfma_f32_16x16x32_bf16(a, b, c, 0, 0, 0);
}

#define PJ_N 13824   // [q 0:1536][k0][k1][v0 4608:][v1 7680:][gate 10752:]
#define NTOK 2048    // B*T rows

// ---------------------------------------------------------------------------
// fp32 -> bf16 bulk convert (for x). n multiple of 8.
__global__ __launch_bounds__(256) void cvt_bf16(
    const float* __restrict__ src, short* __restrict__ dst, int n)
{
  int i = (blockIdx.x * 256 + threadIdx.x) * 8;
  if (i + 8 <= n) {
    float4 a = *(const float4*)(src + i);
    float4 b = *(const float4*)(src + i + 4);
    short v[8] = {f2bf(a.x), f2bf(a.y), f2bf(a.z), f2bf(a.w),
                  f2bf(b.x), f2bf(b.y), f2bf(b.z), f2bf(b.w)};
    uint4 u; __builtin_memcpy(&u, v, 16);
    *(uint4*)(dst + i) = u;
  }
}

// ---------------------------------------------------------------------------
// Weight transpose + convert: W (K x N, fp32) -> WT (N x K, bf16).
__global__ __launch_bounds__(256) void transpose_w(
    const float* __restrict__ W, short* __restrict__ WT, int K, int N)
{
  int lane = threadIdx.x & 63, y = threadIdx.x >> 6;
  int n = blockIdx.x * 64 + lane;
  for (int k0 = y * 8; k0 < K; k0 += 32) {
    short v[8];
    #pragma unroll
    for (int j = 0; j < 8; ++j) v[j] = f2bf(W[(size_t)(k0 + j) * N + n]);
    uint4 u; __builtin_memcpy(&u, v, 16);
    *(uint4*)(WT + (size_t)n * K + k0) = u;
  }
}

// ---------------------------------------------------------------------------
// GEMM: C[M,N] = A[M,K] @ B, given BT (N x K). bf16 in, fp32 accum.
// Grid: (M/128, N/128) — blockIdx.x (fastest) = M-tile, so consecutive
// blocks share one B-tile (L2/L3 reuse; B fetched from HBM ~once).
template<bool F32OUT>
__global__ __launch_bounds__(256) void gemm_bt(
    const short* __restrict__ A, const short* __restrict__ BT,
    void* __restrict__ Cp, int M, int N, int K)
{
  __shared__ short As[128 * 72];
  __shared__ short Bs[128 * 72];
  const int tid = threadIdx.x;
  const int lane = tid & 63, wv = tid >> 6;
  const int quad = lane >> 4, l16 = lane & 15;
  const int m0 = blockIdx.x * 128, n0 = blockIdx.y * 128;
  const int wm = (wv >> 1) * 64, wn = (wv & 1) * 64;
  const int srow = tid >> 1, sseg = (tid & 1) * 32;
  f32x4 zz = {0.f, 0.f, 0.f, 0.f};
  f32x4 acc[4][4];
  #pragma unroll
  for (int i = 0; i < 4; ++i)
    #pragma unroll
    for (int j = 0; j < 4; ++j) acc[i][j] = zz;
  const short* ga = A + (size_t)(m0 + srow) * K + sseg;
  const short* gb = BT + (size_t)(n0 + srow) * K + sseg;
  for (int k0 = 0; k0 < K; k0 += 64) {
    uint4 va[4], vb[4];
    #pragma unroll
    for (int e = 0; e < 4; ++e) {
      va[e] = *(const uint4*)(ga + k0 + e * 8);
      vb[e] = *(const uint4*)(gb + k0 + e * 8);
    }
    __syncthreads();
    #pragma unroll
    for (int e = 0; e < 4; ++e) {
      *(uint4*)(As + srow * 72 + sseg + e * 8) = va[e];
      *(uint4*)(Bs + srow * 72 + sseg + e * 8) = vb[e];
    }
    __syncthreads();
    #pragma unroll
    for (int kk = 0; kk < 64; kk += 32) {
      bf16x8 af[4], bfr[4];
      #pragma unroll
      for (int i = 0; i < 4; ++i)
        af[i] = *(const bf16x8*)(As + (wm + i * 16 + l16) * 72 + kk + quad * 8);
      #pragma unroll
      for (int j = 0; j < 4; ++j)
        bfr[j] = *(const bf16x8*)(Bs + (wn + j * 16 + l16) * 72 + kk + quad * 8);
      #pragma unroll
      for (int i = 0; i < 4; ++i)
        #pragma unroll
        for (int j = 0; j < 4; ++j)
          acc[i][j] = MFMA(af[i], bfr[j], acc[i][j]);
    }
  }
  #pragma unroll
  for (int i = 0; i < 4; ++i)
    #pragma unroll
    for (int j = 0; j < 4; ++j)
      #pragma unroll
      for (int r = 0; r < 4; ++r) {
        int row = m0 + wm + i * 16 + quad * 4 + r;
        int col = n0 + wn + j * 16 + l16;
        if (F32OUT) ((float*)Cp)[(size_t)row * N + col] = acc[i][j][r];
        else        ((short*)Cp)[(size_t)row * N + col] = f2bf(acc[i][j][r]);
      }
}

// ---------------------------------------------------------------------------
// beta (sigmoid(x@b_ws[i])) and g (-exp(A_log)*softplus(x@a_w+dt_bias)).
__global__ __launch_bounds__(64) void proj_small(
    const float* __restrict__ x, const float* __restrict__ b_ws,
    const float* __restrict__ a_w, const float* __restrict__ A_log,
    const float* __restrict__ dt_bias,
    float* __restrict__ Beta0, float* __restrict__ Beta1, float* __restrict__ G)
{
  int row = blockIdx.x, lane = threadIdx.x;
  float p[18];
  #pragma unroll
  for (int j = 0; j < 18; ++j) p[j] = 0.f;
  for (int k = lane; k < 2048; k += 64) {
    float xv = x[(size_t)row * 2048 + k];
    const float* b0 = b_ws + (size_t)k * 6;
    const float* b1 = b_ws + (size_t)2048 * 6 + (size_t)k * 6;
    const float* aw = a_w + (size_t)k * 6;
    #pragma unroll
    for (int j = 0; j < 6; ++j) {
      p[j]      += xv * b0[j];
      p[6 + j]  += xv * b1[j];
      p[12 + j] += xv * aw[j];
    }
  }
  #pragma unroll
  for (int j = 0; j < 18; ++j) {
    #pragma unroll
    for (int off = 32; off > 0; off >>= 1)
      p[j] += __shfl_down(p[j], off);
  }
  if (lane == 0) {
    #pragma unroll
    for (int j = 0; j < 6; ++j) {
      Beta0[(size_t)row * 6 + j] = 1.f / (1.f + expf(-p[j]));
      Beta1[(size_t)row * 6 + j] = 1.f / (1.f + expf(-p[6 + j]));
      float z = p[12 + j] + dt_bias[j];
      float sp = (z > 15.f) ? z : log1pf(expf(z));
      G[(size_t)row * 6 + j] = -expf(A_log[j]) * sp;
    }
  }
}

// ---------------------------------------------------------------------------
// Conv(K=4 causal, depthwise) + SiLU + per-head l2norm (q/k). grid (2048, 6).
__global__ __launch_bounds__(256) void conv_norm_qk(
    const short* __restrict__ P, const float* __restrict__ convw,
    short* __restrict__ dst, int colofs, float scale)
{
  __shared__ float red[256];
  int c = threadIdx.x, h = blockIdx.y, row = blockIdx.x;
  int t = row & 1023;
  int ch = colofs + h * 256 + c;
  const float* cw = convw + (size_t)(h * 256 + c) * 4;
  float acc = 0.f;
  #pragma unroll
  for (int j = 0; j < 4; ++j) {
    int tt = t - 3 + j;
    if (tt >= 0) acc += bf2f(P[(size_t)(row - 3 + j) * PJ_N + ch]) * cw[j];
  }
  float y = acc / (1.f + expf(-acc));   // silu
  red[c] = y * y;
  __syncthreads();
  for (int s = 128; s > 0; s >>= 1) {
    if (c < s) red[c] += red[c + s];
    __syncthreads();
  }
  float nrm = rsqrtf(red[0] + 1e-12f) * scale;
  dst[((size_t)row * 6 + h) * 256 + c] = f2bf(y * nrm);
}

// Conv + SiLU for v. grid (2048, 12).
__global__ __launch_bounds__(256) void conv_v(
    const short* __restrict__ P, const float* __restrict__ convw,
    short* __restrict__ dst, int colofs)
{
  int cg = blockIdx.y * 256 + threadIdx.x;
  int row = blockIdx.x;
  int t = row & 1023;
  const float* cw = convw + (size_t)cg * 4;
  float acc = 0.f;
  #pragma unroll
  for (int j = 0; j < 4; ++j) {
    int tt = t - 3 + j;
    if (tt >= 0) acc += bf2f(P[(size_t)(row - 3 + j) * PJ_N + colofs + cg]) * cw[j];
  }
  float y = acc / (1.f + expf(-acc));
  dst[(size_t)row * 3072 + cg] = f2bf(y);
}

// ---------------------------------------------------------------------------
// Per-(b,h,chunk) precompute of WY operands. grid (32, 6, 2), block 256.
// Qg/Mm store only odd interleaved rows (32 per chunk).
#define KBLD 264
#define R2LD 72
#define WTLD 72
__global__ __launch_bounds__(256) void precompute_chunk(
    const short* __restrict__ Qc, const short* __restrict__ K0c, const short* __restrict__ K1c,
    const short* __restrict__ V0c, const short* __restrict__ V1c,
    const float* __restrict__ Beta0, const float* __restrict__ Beta1, const float* __restrict__ G,
    short* __restrict__ NTW, short* __restrict__ Qg, short* __restrict__ KdT,
    short* __restrict__ Mm, short* __restrict__ TBV, float* __restrict__ dC)
{
  __shared__ short r0[256 * 72];   // kb (64 x KBLD) -> wt (256 x WTLD) -> BVT
  __shared__ float Xs[64 * 64];    // (I+A)^-1 (f32)
  __shared__ short r2[64 * 72];    // KK^T (bf16) -> X (bf16)
  const int tid = threadIdx.x;
  const int lane = tid & 63, wv = tid >> 6;
  const int quad = lane >> 4, l16 = lane & 15;
  const int c = blockIdx.x, h = blockIdx.y, b = blockIdx.z;
  const int i0 = c * 32;
  const size_t idx = (size_t)((b * 6 + h) * 32 + c);
  short* kb = r0;
  f32x4 zz = {0.f, 0.f, 0.f, 0.f};
  bf16x8 z8 = {0, 0, 0, 0, 0, 0, 0, 0};

  // per-lane g/beta for interleaved position t = lane; wave-prefix cumsum
  float gv, betaL;
  {
    int t = lane, par = t & 1, i = i0 + (t >> 1);
    size_t gofs = (size_t)(b * 1024 + i) * 6 + h;
    gv = par ? 0.f : G[gofs];
    betaL = par ? Beta1[gofs] : Beta0[gofs];
  }
  float cum = gv;
  #pragma unroll
  for (int off = 1; off < 64; off <<= 1) {
    float nb = __shfl_up(cum, off);
    if (lane >= off) cum += nb;
  }
  float c63 = __shfl(cum, 63);
  float eBt = expf(cum);          // exp(B_t)
  float eRem = expf(c63 - cum);   // exp(B63 - B_t)
  float wsc = betaL * eBt;        // beta_t exp(B_t)
  if (tid == 0) dC[idx] = expf(c63);

  // stage k chunk (interleaved parities) into kb
  {
    int row = tid >> 2, seg = (tid & 3) * 64;
    int par = row & 1, i = i0 + (row >> 1);
    const short* src = (par ? K1c : K0c) + ((size_t)(b * 1024 + i) * 6 + h) * 256 + seg;
    short* dp = kb + row * KBLD + seg;
    #pragma unroll
    for (int e = 0; e < 64; e += 8)
      *(uint4*)(dp + e) = *(const uint4*)(src + e);
  }
  __syncthreads();

  // KK^T (bf16 into r2). wave = t row-tile.
  {
    f32x4 acc[4];
    #pragma unroll
    for (int ts = 0; ts < 4; ++ts) acc[ts] = zz;
    #pragma unroll
    for (int ks = 0; ks < 8; ++ks) {
      bf16x8 af = *(const bf16x8*)(kb + (wv * 16 + l16) * KBLD + ks * 32 + quad * 8);
      #pragma unroll
      for (int ts = 0; ts < 4; ++ts) {
        bf16x8 bfv = *(const bf16x8*)(kb + (ts * 16 + l16) * KBLD + ks * 32 + quad * 8);
        acc[ts] = MFMA(af, bfv, acc[ts]);
      }
    }
    #pragma unroll
    for (int ts = 0; ts < 4; ++ts)
      #pragma unroll
      for (int r = 0; r < 4; ++r)
        r2[(wv * 16 + quad * 4 + r) * R2LD + ts * 16 + l16] = f2bf(acc[ts][r]);
  }
  // QK^T -> M (masked, decayed; odd rows only) directly to global
  {
    f32x4 acc[4];
    #pragma unroll
    for (int ts = 0; ts < 4; ++ts) acc[ts] = zz;
    int t_row = wv * 16 + l16;
    int podd = t_row & 1, iq = i0 + (t_row >> 1);
    const short* qrow = Qc + ((size_t)(b * 1024 + iq) * 6 + h) * 256;
    #pragma unroll
    for (int ks = 0; ks < 8; ++ks) {
      bf16x8 af = z8;
      if (podd) af = *(const bf16x8*)(qrow + ks * 32 + quad * 8);
      #pragma unroll
      for (int ts = 0; ts < 4; ++ts) {
        bf16x8 bfv = *(const bf16x8*)(kb + (ts * 16 + l16) * KBLD + ks * 32 + quad * 8);
        acc[ts] = MFMA(af, bfv, acc[ts]);
      }
    }
    short* Mp = Mm + idx * 2048;
    #pragma unroll
    for (int ts = 0; ts < 4; ++ts)
      #pragma unroll
      for (int r = 1; r < 4; r += 2) {       // odd rows only
        int t = wv * 16 + quad * 4 + r, s = ts * 16 + l16;
        float ct = __shfl(cum, t), cs = __shfl(cum, s);
        float v = (s <= t) ? acc[ts][r] * expf(ct - cs) : 0.f;
        Mp[(t >> 1) * 64 + s] = f2bf(v);
      }
  }
  // Qg (odd rows only): Qg[th][d] = exp(B_{2th+1}) q_{2th+1}[d]
  {
    int th = tid >> 3, dseg = (tid & 7) * 32;
    int t = th * 2 + 1;
    float sc = __shfl(eBt, t);
    const short* qrow = Qc + ((size_t)(b * 1024 + i0 + th) * 6 + h) * 256 + dseg;
    short* qgp = Qg + idx * 8192 + (size_t)th * 256 + dseg;
    #pragma unroll
    for (int e = 0; e < 32; e += 8) {
      bf16x8 v = *(const bf16x8*)(qrow + e);
      bf16x8 w;
      #pragma unroll
      for (int q2 = 0; q2 < 8; ++q2) w[q2] = f2bf(bf2f(v[q2]) * sc);
      *(bf16x8*)(qgp + e) = w;
    }
  }
  // KdT[d][t] = exp(B63-B_t) k_t[d]
  {
    int d = tid;
    short buf[64];
    #pragma unroll
    for (int t = 0; t < 64; ++t) {
      float sc = __shfl(eRem, t);
      buf[t] = f2bf(bf2f(kb[t * KBLD + d]) * sc);
    }
    short* kp = KdT + idx * 16384 + (size_t)d * 64;
    #pragma unroll
    for (int e = 0; e < 64; e += 8) {
      uint4 v; __builtin_memcpy(&v, buf + e, 16);
      *(uint4*)(kp + e) = v;
    }
  }
  __syncthreads();

  // C1: cache kb column d = tid in registers
  short colv[64];
  {
    int d = tid;
    #pragma unroll
    for (int t = 0; t < 64; ++t) colv[t] = kb[t * KBLD + d];
  }
  __syncthreads();
  // C2: wt[d][s] = beta_s exp(B_s) k_s[d] (over r0)
  {
    int d = tid;
    short wrow[64];
    #pragma unroll
    for (int s = 0; s < 64; ++s) wrow[s] = f2bf(bf2f(colv[s]) * __shfl(wsc, s));
    short* wp = r0 + d * WTLD;
    #pragma unroll
    for (int e = 0; e < 64; e += 8) {
      uint4 v; __builtin_memcpy(&v, wrow + e, 16);
      *(uint4*)(wp + e) = v;
    }
  }
  // C3: wave0 solves X = (I+A)^-1 by forward substitution (cols = lanes)
  if (wv == 0) {
    int j = lane;
    for (int t = 0; t < 64; ++t) {
      float bt = __shfl(betaL, t);
      float ct = __shfl(cum, t);
      float sacc = 0.f;
      for (int s = 0; s < t; ++s) {
        float cs = __shfl(cum, s);
        float a = bt * expf(ct - cs) * bf2f(r2[t * R2LD + s]);
        sacc += a * Xs[s * 64 + j];
      }
      Xs[t * 64 + j] = ((t == j) ? 1.f : 0.f) - sacc;
    }
  }
  __syncthreads();
  // X -> r2 (bf16)
  for (int e = tid; e < 4096; e += 256) {
    int t = e >> 6, s = e & 63;
    r2[t * R2LD + s] = f2bf(Xs[e]);
  }
  __syncthreads();
  // NTW = -(X @ W)
  {
    f32x4 acc[4][4];
    #pragma unroll
    for (int i = 0; i < 4; ++i)
      #pragma unroll
      for (int j = 0; j < 4; ++j) acc[i][j] = zz;
    #pragma unroll
    for (int ks = 0; ks < 2; ++ks) {
      bf16x8 af[4], bfv[4];
      #pragma unroll
      for (int tt = 0; tt < 4; ++tt)
        af[tt] = *(const bf16x8*)(r2 + (tt * 16 + l16) * R2LD + ks * 32 + quad * 8);
      #pragma unroll
      for (int dt = 0; dt < 4; ++dt)
        bfv[dt] = *(const bf16x8*)(r0 + ((wv * 4 + dt) * 16 + l16) * WTLD + ks * 32 + quad * 8);
      #pragma unroll
      for (int tt = 0; tt < 4; ++tt)
        #pragma unroll
        for (int dt = 0; dt < 4; ++dt)
          acc[tt][dt] = MFMA(af[tt], bfv[dt], acc[tt][dt]);
    }
    short* np = NTW + idx * 16384;
    #pragma unroll
    for (int tt = 0; tt < 4; ++tt)
      #pragma unroll
      for (int dt = 0; dt < 4; ++dt)
        #pragma unroll
        for (int r = 0; r < 4; ++r) {
          int t = tt * 16 + quad * 4 + r, d = (wv * 4 + dt) * 16 + l16;
          np[t * 256 + d] = f2bf(-acc[tt][dt][r]);
        }
  }
  __syncthreads();
  // TBV = X @ (beta*v), two DV halves through r0
  for (int vh = 0; vh < 2; ++vh) {
    {
      int vl = tid;
      short bv[64];
      #pragma unroll
      for (int t = 0; t < 64; ++t) {
        int par = t & 1, i = i0 + (t >> 1);
        const short* src = (par ? V1c : V0c) + (size_t)(b * 1024 + i) * 3072 + h * 512 + vh * 256 + vl;
        bv[t] = f2bf(bf2f(*src) * __shfl(betaL, t));
      }
      short* bp = r0 + vl * WTLD;
      #pragma unroll
      for (int e = 0; e < 64; e += 8) {
        uint4 v; __builtin_memcpy(&v, bv + e, 16);
        *(uint4*)(bp + e) = v;
      }
    }
    __syncthreads();
    {
      f32x4 acc[4][4];
      #pragma unroll
      for (int i = 0; i < 4; ++i)
        #pragma unroll
        for (int j = 0; j < 4; ++j) acc[i][j] = zz;
      #pragma unroll
      for (int ks = 0; ks < 2; ++ks) {
        bf16x8 af[4], bfv[4];
        #pragma unroll
        for (int tt = 0; tt < 4; ++tt)
          af[tt] = *(const bf16x8*)(r2 + (tt * 16 + l16) * R2LD + ks * 32 + quad * 8);
        #pragma unroll
        for (int vt = 0; vt < 4; ++vt)
          bfv[vt] = *(const bf16x8*)(r0 + ((wv * 4 + vt) * 16 + l16) * WTLD + ks * 32 + quad * 8);
        #pragma unroll
        for (int tt = 0; tt < 4; ++tt)
          #pragma unroll
          for (int vt = 0; vt < 4; ++vt)
            acc[tt][vt] = MFMA(af[tt], bfv[vt], acc[tt][vt]);
      }
      short* tp = TBV + idx * 32768;
      #pragma unroll
      for (int tt = 0; tt < 4; ++tt)
        #pragma unroll
        for (int vt = 0; vt < 4; ++vt)
          #pragma unroll
          for (int r = 0; r < 4; ++r) {
            int t = tt * 16 + quad * 4 + r, v = (wv * 4 + vt) * 16 + l16;
            tp[t * 512 + vh * 256 + v] = f2bf(acc[tt][vt][r]);
          }
    }
    __syncthreads();
  }
}

// ---------------------------------------------------------------------------
// Scan: one wave per (b,h,16-col slice of DV). grid 384, block 64.
#define SLD 264
#define ULD 72
__global__ __launch_bounds__(64) void scan_kernel(
    const short* __restrict__ NTW, const short* __restrict__ Qg,
    const short* __restrict__ KdT, const short* __restrict__ Mm,
    const short* __restrict__ TBV, const float* __restrict__ dC,
    short* __restrict__ O)
{
  __shared__ short S[16 * SLD];   // state slice, [v_local][d], bf16
  __shared__ short U[16 * ULD];   // u slice, [v_local][t], bf16
  int lane = threadIdx.x;
  int quad = lane >> 4, l16 = lane & 15;
  int bh = blockIdx.x >> 5, slice = blockIdx.x & 31;
  int b = bh / 6, h = bh % 6;
  int vbase = slice * 16;
  f32x4 zz = {0.f, 0.f, 0.f, 0.f};
  for (int e = lane; e < 16 * SLD; e += 64) S[e] = 0;
  __syncthreads();

  for (int c = 0; c < 32; ++c) {
    size_t idx = (size_t)(bh * 32 + c);
    const short* ntw = NTW + idx * 16384;
    const short* qg  = Qg  + idx * 8192;
    const short* kdt = KdT + idx * 16384;
    const short* mp  = Mm  + idx * 2048;
    const short* tb  = TBV + idx * 32768;
    float dc = dC[idx];

    // u = NTW @ S0 + TBV
    f32x4 uac[4];
    #pragma unroll
    for (int tt = 0; tt < 4; ++tt)
      #pragma unroll
      for (int r = 0; r < 4; ++r)
        uac[tt][r] = bf2f(tb[(size_t)(tt * 16 + quad * 4 + r) * 512 + vbase + l16]);
    #pragma unroll
    for (int ks = 0; ks < 8; ++ks) {
      bf16x8 bfv = *(const bf16x8*)(S + l16 * SLD + ks * 32 + quad * 8);
      #pragma unroll
      for (int tt = 0; tt < 4; ++tt) {
        bf16x8 af = *(const bf16x8*)(ntw + (tt * 16 + l16) * 256 + ks * 32 + quad * 8);
        uac[tt] = MFMA(af, bfv, uac[tt]);
      }
    }
    #pragma unroll
    for (int tt = 0; tt < 4; ++tt)
      #pragma unroll
      for (int r = 0; r < 4; ++r)
        U[l16 * ULD + tt * 16 + quad * 4 + r] = f2bf(uac[tt][r]);
    __syncthreads();

    // o = Qg @ S0 + M @ u   (odd interleaved rows, 32 of them)
    f32x4 oac[2];
    #pragma unroll
    for (int tt = 0; tt < 2; ++tt) oac[tt] = zz;
    #pragma unroll
    for (int ks = 0; ks < 8; ++ks) {
      bf16x8 bfv = *(const bf16x8*)(S + l16 * SLD + ks * 32 + quad * 8);
      #pragma unroll
      for (int tt = 0; tt < 2; ++tt) {
        bf16x8 af = *(const bf16x8*)(qg + (tt * 16 + l16) * 256 + ks * 32 + quad * 8);
        oac[tt] = MFMA(af, bfv, oac[tt]);
      }
    }
    #pragma unroll
    for (int ks = 0; ks < 2; ++ks) {
      bf16x8 bfv = *(const bf16x8*)(U + l16 * ULD + ks * 32 + quad * 8);
      #pragma unroll
      for (int tt = 0; tt < 2; ++tt) {
        bf16x8 af = *(const bf16x8*)(mp + (tt * 16 + l16) * 64 + ks * 32 + quad * 8);
        oac[tt] = MFMA(af, bfv, oac[tt]);
      }
    }
    #pragma unroll
    for (int tt = 0; tt < 2; ++tt) {
      #pragma unroll
      for (int r = 0; r < 4; ++r) {
        int th = tt * 16 + quad * 4 + r;
        int i = c * 32 + th;
        O[((size_t)(b * 1024 + i) * 6 + h) * 512 + vbase + l16] = f2bf(oac[tt][r]);
      }
    }
    __syncthreads();

    // S1 = dc * S0 + KdT @ u
    #pragma unroll
    for (int g2 = 0; g2 < 4; ++g2) {
      f32x4 sac[4];
      #pragma unroll
      for (int dt = 0; dt < 4; ++dt)
        #pragma unroll
        for (int r = 0; r < 4; ++r)
          sac[dt][r] = dc * bf2f(S[l16 * SLD + (g2 * 4 + dt) * 16 + quad * 4 + r]);
      #pragma unroll
      for (int ks = 0; ks < 2; ++ks) {
        bf16x8 bfv = *(const bf16x8*)(U + l16 * ULD + ks * 32 + quad * 8);
        #pragma unroll
        for (int dt = 0; dt < 4; ++dt) {
          bf16x8 af = *(const bf16x8*)(kdt + ((g2 * 4 + dt) * 16 + l16) * 64 + ks * 32 + quad * 8);
          sac[dt] = MFMA(af, bfv, sac[dt]);
        }
      }
      #pragma unroll
      for (int dt = 0; dt < 4; ++dt)
        #pragma unroll
        for (int r = 0; r < 4; ++r)
          S[l16 * SLD + (g2 * 4 + dt) * 16 + quad * 4 + r] = f2bf(sac[dt][r]);
    }
    __syncthreads();
  }
}

// ---------------------------------------------------------------------------
// RMS-norm over DV per (b,t,h), times silu(gate). grid (2048, 6).
__global__ __launch_bounds__(256) void rms_gate(
    const short* __restrict__ O, const short* __restrict__ P,
    const float* __restrict__ onw, short* __restrict__ OutPre)
{
  __shared__ float red[256];
  int tid = threadIdx.x, h = blockIdx.y, row = blockIdx.x;
  size_t base = ((size_t)row * 6 + h) * 512;
  float a = bf2f(O[base + tid]), b2 = bf2f(O[base + 256 + tid]);
  red[tid] = a * a + b2 * b2;
  __syncthreads();
  for (int s = 128; s > 0; s >>= 1) {
    if (tid < s) red[tid] += red[tid + s];
    __syncthreads();
  }
  float r = rsqrtf(red[0] * (1.f / 512.f) + 1e-5f);
  #pragma unroll
  for (int half = 0; half < 2; ++half) {
    int col = tid + half * 256;
    float ov = half ? b2 : a;
    float g = bf2f(P[(size_t)row * PJ_N + 10752 + h * 512 + col]);
    float sg = g / (1.f + expf(-g));
    OutPre[(size_t)row * 3072 + h * 512 + col] = f2bf(ov * r * onw[col] * sg);
  }
}

// ---------------------------------------------------------------------------
extern "C" void kernel_launch(void* const* d_in, const int* in_sizes, int n_in,
                              void* d_out, int out_size, void* d_ws, size_t ws_size,
                              hipStream_t stream) {
  const float* x        = (const float*)d_in[0];
  const float* q_w      = (const float*)d_in[1];
  const float* k_ws     = (const float*)d_in[2];
  const float* v_ws     = (const float*)d_in[3];
  const float* b_ws     = (const float*)d_in[4];
  const float* a_w      = (const float*)d_in[5];
  const float* g_w      = (const float*)d_in[6];
  const float* o_w      = (const float*)d_in[7];
  const float* q_conv_w = (const float*)d_in[8];
  const float* k_conv   = (const float*)d_in[9];
  const float* v_conv   = (const float*)d_in[10];
  const float* A_log    = (const float*)d_in[11];
  const float* dt_bias  = (const float*)d_in[12];
  const float* o_norm_w = (const float*)d_in[13];
  float* out = (float*)d_out;

  char* ws = (char*)d_ws;
  size_t off = 0;
  auto take = [&](size_t bytes) {
    size_t r = off;
    off += (bytes + 255) & ~(size_t)255;
    return r;
  };
  // Persistent buffers
  short* P  = (short*)(ws + take((size_t)NTOK * PJ_N * 2));   // live 3-8
  short* oT = (short*)(ws + take((size_t)2048 * 3072 * 2));   // live 2-9
  // xbf (step 3 only) reused for Mm (steps 6-7)
  size_t regX = take((size_t)NTOK * 2048 * 2);                // 8.39 MB
  short* xbf = (short*)(ws + regX);
  short* Mm  = (short*)(ws + regX);                           // 1.57 MB
  // Region A: WTall (steps 2-3) reused for NTW|Qg|KdT|TBV (steps 6-7)
  size_t regA = take((size_t)PJ_N * 2048 * 2);                // 56,623,104 B
  short* WTall = (short*)(ws + regA);
  short* NTW = (short*)(ws + regA);
  short* Qg  = NTW + (size_t)384 * 16384;
  short* KdT = Qg  + (size_t)384 * 8192;
  short* TBV = KdT + (size_t)384 * 16384;   // ends exactly at regA + 56,623,104
  // Region B: conv outputs (steps 5-6) reused for O/OutPre (steps 7-9)
  size_t regB = take((size_t)44040192);                       // 44.0 MB
  short* Qc  = (short*)(ws + regB);
  short* K0c = Qc  + (size_t)NTOK * 1536;
  short* K1c = K0c + (size_t)NTOK * 1536;
  short* V0c = K1c + (size_t)NTOK * 1536;
  short* V1c = V0c + (size_t)NTOK * 3072;
  short* O      = (short*)(ws + regB);                        // 12.6 MB
  short* OutPre = O + (size_t)NTOK * 6 * 512;                 // 12.6 MB
  float* Beta0 = (float*)(ws + take((size_t)NTOK * 6 * 4));
  float* Beta1 = (float*)(ws + take((size_t)NTOK * 6 * 4));
  float* G     = (float*)(ws + take((size_t)NTOK * 6 * 4));
  float* dCp   = (float*)(ws + take((size_t)384 * 4));
  if (off > ws_size) return;  // ws too small: no-op (diagnosable, capture-safe)

  // 1) convert x to bf16
  cvt_bf16<<<dim3(NTOK * 2048 / 8 / 256), 256, 0, stream>>>(x, xbf, NTOK * 2048);

  // 2) weight transposes (fp32 -> bf16) into WTall [q|k0|k1|v0|v1|gate] and oT
  transpose_w<<<dim3(24), 256, 0, stream>>>(q_w, WTall, 2048, 1536);
  transpose_w<<<dim3(24), 256, 0, stream>>>(k_ws, WTall + (size_t)1536 * 2048, 2048, 1536);
  transpose_w<<<dim3(24), 256, 0, stream>>>(k_ws + (size_t)2048 * 1536, WTall + (size_t)3072 * 2048, 2048, 1536);
  transpose_w<<<dim3(48), 256, 0, stream>>>(v_ws, WTall + (size_t)4608 * 2048, 2048, 3072);
  transpose_w<<<dim3(48), 256, 0, stream>>>(v_ws + (size_t)2048 * 3072, WTall + (size_t)7680 * 2048, 2048, 3072);
  transpose_w<<<dim3(48), 256, 0, stream>>>(g_w, WTall + (size_t)10752 * 2048, 2048, 3072);
  transpose_w<<<dim3(32), 256, 0, stream>>>(o_w, oT, 3072, 2048);

  // 3) fused projection GEMM: P = x @ [q_w|k0|k1|v0|v1|g_w]  (bf16 out)
  //    grid: M-tiles fastest (B-tile L2 reuse across co-resident blocks)
  gemm_bt<false><<<dim3(NTOK / 128, PJ_N / 128), 256, 0, stream>>>(
      xbf, WTall, P, NTOK, PJ_N, 2048);

  // 4) beta / g (fp32 inputs straight from d_in)
  proj_small<<<dim3(NTOK), 64, 0, stream>>>(x, b_ws, a_w, A_log, dt_bias, Beta0, Beta1, G);

  // 5) conv + silu (+ l2norm for q/k)
  conv_norm_qk<<<dim3(NTOK, 6), 256, 0, stream>>>(P, q_conv_w, Qc, 0, 0.0625f);
  conv_norm_qk<<<dim3(NTOK, 6), 256, 0, stream>>>(P, k_conv, K0c, 1536, 1.f);
  conv_norm_qk<<<dim3(NTOK, 6), 256, 0, stream>>>(P, k_conv + (size_t)1536 * 4, K1c, 3072, 1.f);
  conv_v<<<dim3(NTOK, 12), 256, 0, stream>>>(P, v_conv, V0c, 4608);
  conv_v<<<dim3(NTOK, 12), 256, 0, stream>>>(P, v_conv + (size_t)3072 * 4, V1c, 7680);

  // 6) chunk operand precompute (WY form)
  precompute_chunk<<<dim3(32, 6, 2), 256, 0, stream>>>(Qc, K0c, K1c, V0c, V1c,
      Beta0, Beta1, G, NTW, Qg, KdT, Mm, TBV, dCp);

  // 7) sequential chunk scan (384 independent waves)
  scan_kernel<<<dim3(384), 64, 0, stream>>>(NTW, Qg, KdT, Mm, TBV, dCp, O);

  // 8) rms-norm * silu(gate)
  rms_gate<<<dim3(NTOK, 6), 256, 0, stream>>>(O, P, o_norm_w, OutPre);

  // 9) output projection (fp32 out), same col-major swizzle
  gemm_bt<true><<<dim3(NTOK / 128, 2048 / 128), 256, 0, stream>>>(
      OutPre, oT, out, NTOK, 2048, 3072);
}

// Round 7
// 1818.418 us; speedup vs baseline: 2.4352x; 1.2729x over previous
//
#include <hip/hip_runtime.h>

// ---------------------------------------------------------------------------
// GatedDeltaProduct: B=2,T=1024,HID=2048, NH=2, H=6, DK=256, DV=512, CHUNK=64
// Inputs fp32, output fp32. Internal bf16 MFMA. WY chunked gated delta rule.
// R7: m97-style global_load_lds GEMM (XOR-swizzled LDS), XCD-aware grid,
//     scan waves grouped 4/block for L1 operand sharing.
// ---------------------------------------------------------------------------

typedef short bf16x8 __attribute__((ext_vector_type(8)));
typedef float f32x4 __attribute__((ext_vector_type(4)));

__device__ __forceinline__ float bf2f(short s) {
  unsigned u = ((unsigned)(unsigned short)s) << 16;
  float f; __builtin_memcpy(&f, &u, 4); return f;
}
__device__ __forceinline__ short f2bf(float f) {
  unsigned u; __builtin_memcpy(&u, &f, 4);
  u = (u + 0x7FFFu + ((u >> 16) & 1u)) >> 16;
  return (short)u;
}
__device__ __forceinline__ f32x4 MFMA(bf16x8 a, bf16x8 b, f32x4 c) {
  return __builtin_amdgcn_mfma_f32_16x16x32_bf16(a, b, c, 0, 0, 0);
}
// async global->LDS, 16B per lane; lds dest = wave-uniform base + lane*16
__device__ __forceinline__ void gl_lds16(const short* g, short* l) {
  __builtin_amdgcn_global_load_lds(
      (const __attribute__((address_space(1))) unsigned int*)g,
      (__attribute__((address_space(3))) unsigned int*)l, 16, 0, 0);
}

#define PJ_N 13824   // [q 0:1536][k0][k1][v0 4608:][v1 7680:][gate 10752:]
#define NTOK 2048    // B*T rows

// ---------------------------------------------------------------------------
// fp32 -> bf16 bulk convert (for x). n multiple of 8.
__global__ __launch_bounds__(256) void cvt_bf16(
    const float* __restrict__ src, short* __restrict__ dst, int n)
{
  int i = (blockIdx.x * 256 + threadIdx.x) * 8;
  if (i + 8 <= n) {
    float4 a = *(const float4*)(src + i);
    float4 b = *(const float4*)(src + i + 4);
    short v[8] = {f2bf(a.x), f2bf(a.y), f2bf(a.z), f2bf(a.w),
                  f2bf(b.x), f2bf(b.y), f2bf(b.z), f2bf(b.w)};
    uint4 u; __builtin_memcpy(&u, v, 16);
    *(uint4*)(dst + i) = u;
  }
}

// ---------------------------------------------------------------------------
// Weight transpose + convert: W (K x N, fp32) -> WT (N x K, bf16).
__global__ __launch_bounds__(256) void transpose_w(
    const float* __restrict__ W, short* __restrict__ WT, int K, int N)
{
  int lane = threadIdx.x & 63, y = threadIdx.x >> 6;
  int n = blockIdx.x * 64 + lane;
  for (int k0 = y * 8; k0 < K; k0 += 32) {
    short v[8];
    #pragma unroll
    for (int j = 0; j < 8; ++j) v[j] = f2bf(W[(size_t)(k0 + j) * N + n]);
    uint4 u; __builtin_memcpy(&u, v, 16);
    *(uint4*)(WT + (size_t)n * K + k0) = u;
  }
}

// ---------------------------------------------------------------------------
// GEMM: C[M,N] = A[M,K] @ B, given BT (N x K). bf16 in, fp32 accum.
// M fixed 2048 (16 tiles). 1-D grid, XCD-aware: blk&7 = XCD owns N-subset,
// M fastest within XCD. Unpadded 128x64 LDS tiles staged by global_load_lds
// (16B/lane) with XOR-by-row swizzle: LDS[row][seg] = G[row][seg ^ (row&7)].
template<bool F32OUT>
__global__ __launch_bounds__(256) void gemm_bt(
    const short* __restrict__ A, const short* __restrict__ BT,
    void* __restrict__ Cp, int M, int N, int K)
{
  __shared__ short As[128 * 64];
  __shared__ short Bs[128 * 64];
  const int tid = threadIdx.x;
  const int lane = tid & 63, wv = tid >> 6;
  const int quad = lane >> 4, l16 = lane & 15;
  const int j = blockIdx.x;
  const int xcd = j & 7, local = j >> 3;
  const int mtile = local & 15, ng = local >> 4;
  const int ntile = ng * 8 + xcd;
  if (ntile * 128 >= N) return;     // pad blocks no-op (uniform per block)
  const int m0 = mtile * 128, n0 = ntile * 128;
  const int wm = (wv >> 1) * 64, wn = (wv & 1) * 64;
  const int lrow = lane >> 3;              // 0..7 within staging call
  const int lperm = (lane & 7) ^ lrow;     // xor swizzle source segment
  const int xr = l16 & 7;                  // read-side xor key
  f32x4 zz = {0.f, 0.f, 0.f, 0.f};
  f32x4 acc[4][4];
  #pragma unroll
  for (int i = 0; i < 4; ++i)
    #pragma unroll
    for (int jj = 0; jj < 4; ++jj) acc[i][jj] = zz;

  for (int k0 = 0; k0 < K; k0 += 64) {
    __syncthreads();   // previous tile fully consumed before overwrite
    #pragma unroll
    for (int c = 0; c < 4; ++c) {
      int row = (wv * 4 + c) * 8 + lrow;
      gl_lds16(A  + (size_t)(m0 + row) * K + k0 + lperm * 8,
               As + (wv * 4 + c) * 512);
      gl_lds16(BT + (size_t)(n0 + row) * K + k0 + lperm * 8,
               Bs + (wv * 4 + c) * 512);
    }
    __syncthreads();   // barrier drains vmcnt (compiler-inserted waitcnt)
    #pragma unroll
    for (int kk = 0; kk < 64; kk += 32) {
      const int ksb = kk >> 3;
      bf16x8 af[4], bfr[4];
      #pragma unroll
      for (int i = 0; i < 4; ++i)
        af[i] = *(const bf16x8*)(As + (wm + i * 16 + l16) * 64 +
                                 (((ksb + quad) ^ xr) << 3));
      #pragma unroll
      for (int jj = 0; jj < 4; ++jj)
        bfr[jj] = *(const bf16x8*)(Bs + (wn + jj * 16 + l16) * 64 +
                                   (((ksb + quad) ^ xr) << 3));
      #pragma unroll
      for (int i = 0; i < 4; ++i)
        #pragma unroll
        for (int jj = 0; jj < 4; ++jj)
          acc[i][jj] = MFMA(af[i], bfr[jj], acc[i][jj]);
    }
  }
  #pragma unroll
  for (int i = 0; i < 4; ++i)
    #pragma unroll
    for (int jj = 0; jj < 4; ++jj)
      #pragma unroll
      for (int r = 0; r < 4; ++r) {
        int row = m0 + wm + i * 16 + quad * 4 + r;
        int col = n0 + wn + jj * 16 + l16;
        if (F32OUT) ((float*)Cp)[(size_t)row * N + col] = acc[i][jj][r];
        else        ((short*)Cp)[(size_t)row * N + col] = f2bf(acc[i][jj][r]);
      }
}

// ---------------------------------------------------------------------------
// beta (sigmoid(x@b_ws[i])) and g (-exp(A_log)*softplus(x@a_w+dt_bias)).
__global__ __launch_bounds__(64) void proj_small(
    const float* __restrict__ x, const float* __restrict__ b_ws,
    const float* __restrict__ a_w, const float* __restrict__ A_log,
    const float* __restrict__ dt_bias,
    float* __restrict__ Beta0, float* __restrict__ Beta1, float* __restrict__ G)
{
  int row = blockIdx.x, lane = threadIdx.x;
  float p[18];
  #pragma unroll
  for (int j = 0; j < 18; ++j) p[j] = 0.f;
  for (int k = lane; k < 2048; k += 64) {
    float xv = x[(size_t)row * 2048 + k];
    const float* b0 = b_ws + (size_t)k * 6;
    const float* b1 = b_ws + (size_t)2048 * 6 + (size_t)k * 6;
    const float* aw = a_w + (size_t)k * 6;
    #pragma unroll
    for (int j = 0; j < 6; ++j) {
      p[j]      += xv * b0[j];
      p[6 + j]  += xv * b1[j];
      p[12 + j] += xv * aw[j];
    }
  }
  #pragma unroll
  for (int j = 0; j < 18; ++j) {
    #pragma unroll
    for (int off = 32; off > 0; off >>= 1)
      p[j] += __shfl_down(p[j], off);
  }
  if (lane == 0) {
    #pragma unroll
    for (int j = 0; j < 6; ++j) {
      Beta0[(size_t)row * 6 + j] = 1.f / (1.f + expf(-p[j]));
      Beta1[(size_t)row * 6 + j] = 1.f / (1.f + expf(-p[6 + j]));
      float z = p[12 + j] + dt_bias[j];
      float sp = (z > 15.f) ? z : log1pf(expf(z));
      G[(size_t)row * 6 + j] = -expf(A_log[j]) * sp;
    }
  }
}

// ---------------------------------------------------------------------------
// Conv(K=4 causal, depthwise) + SiLU + per-head l2norm (q/k). grid (2048, 6).
__global__ __launch_bounds__(256) void conv_norm_qk(
    const short* __restrict__ P, const float* __restrict__ convw,
    short* __restrict__ dst, int colofs, float scale)
{
  __shared__ float red[256];
  int c = threadIdx.x, h = blockIdx.y, row = blockIdx.x;
  int t = row & 1023;
  int ch = colofs + h * 256 + c;
  const float* cw = convw + (size_t)(h * 256 + c) * 4;
  float acc = 0.f;
  #pragma unroll
  for (int j = 0; j < 4; ++j) {
    int tt = t - 3 + j;
    if (tt >= 0) acc += bf2f(P[(size_t)(row - 3 + j) * PJ_N + ch]) * cw[j];
  }
  float y = acc / (1.f + expf(-acc));   // silu
  red[c] = y * y;
  __syncthreads();
  for (int s = 128; s > 0; s >>= 1) {
    if (c < s) red[c] += red[c + s];
    __syncthreads();
  }
  float nrm = rsqrtf(red[0] + 1e-12f) * scale;
  dst[((size_t)row * 6 + h) * 256 + c] = f2bf(y * nrm);
}

// Conv + SiLU for v. grid (2048, 12).
__global__ __launch_bounds__(256) void conv_v(
    const short* __restrict__ P, const float* __restrict__ convw,
    short* __restrict__ dst, int colofs)
{
  int cg = blockIdx.y * 256 + threadIdx.x;
  int row = blockIdx.x;
  int t = row & 1023;
  const float* cw = convw + (size_t)cg * 4;
  float acc = 0.f;
  #pragma unroll
  for (int j = 0; j < 4; ++j) {
    int tt = t - 3 + j;
    if (tt >= 0) acc += bf2f(P[(size_t)(row - 3 + j) * PJ_N + colofs + cg]) * cw[j];
  }
  float y = acc / (1.f + expf(-acc));
  dst[(size_t)row * 3072 + cg] = f2bf(y);
}

// ---------------------------------------------------------------------------
// Per-(b,h,chunk) precompute of WY operands. grid (32, 6, 2), block 256.
// Qg/Mm store only odd interleaved rows (32 per chunk).
#define KBLD 264
#define R2LD 72
#define WTLD 72
__global__ __launch_bounds__(256) void precompute_chunk(
    const short* __restrict__ Qc, const short* __restrict__ K0c, const short* __restrict__ K1c,
    const short* __restrict__ V0c, const short* __restrict__ V1c,
    const float* __restrict__ Beta0, const float* __restrict__ Beta1, const float* __restrict__ G,
    short* __restrict__ NTW, short* __restrict__ Qg, short* __restrict__ KdT,
    short* __restrict__ Mm, short* __restrict__ TBV, float* __restrict__ dC)
{
  __shared__ short r0[256 * 72];   // kb (64 x KBLD) -> wt (256 x WTLD) -> BVT
  __shared__ float Xs[64 * 64];    // (I+A)^-1 (f32)
  __shared__ short r2[64 * 72];    // KK^T (bf16) -> X (bf16)
  const int tid = threadIdx.x;
  const int lane = tid & 63, wv = tid >> 6;
  const int quad = lane >> 4, l16 = lane & 15;
  const int c = blockIdx.x, h = blockIdx.y, b = blockIdx.z;
  const int i0 = c * 32;
  const size_t idx = (size_t)((b * 6 + h) * 32 + c);
  short* kb = r0;
  f32x4 zz = {0.f, 0.f, 0.f, 0.f};
  bf16x8 z8 = {0, 0, 0, 0, 0, 0, 0, 0};

  // per-lane g/beta for interleaved position t = lane; wave-prefix cumsum
  float gv, betaL;
  {
    int t = lane, par = t & 1, i = i0 + (t >> 1);
    size_t gofs = (size_t)(b * 1024 + i) * 6 + h;
    gv = par ? 0.f : G[gofs];
    betaL = par ? Beta1[gofs] : Beta0[gofs];
  }
  float cum = gv;
  #pragma unroll
  for (int off = 1; off < 64; off <<= 1) {
    float nb = __shfl_up(cum, off);
    if (lane >= off) cum += nb;
  }
  float c63 = __shfl(cum, 63);
  float eBt = expf(cum);          // exp(B_t)
  float eRem = expf(c63 - cum);   // exp(B63 - B_t)
  float wsc = betaL * eBt;        // beta_t exp(B_t)
  if (tid == 0) dC[idx] = expf(c63);

  // stage k chunk (interleaved parities) into kb
  {
    int row = tid >> 2, seg = (tid & 3) * 64;
    int par = row & 1, i = i0 + (row >> 1);
    const short* src = (par ? K1c : K0c) + ((size_t)(b * 1024 + i) * 6 + h) * 256 + seg;
    short* dp = kb + row * KBLD + seg;
    #pragma unroll
    for (int e = 0; e < 64; e += 8)
      *(uint4*)(dp + e) = *(const uint4*)(src + e);
  }
  __syncthreads();

  // KK^T (bf16 into r2). wave = t row-tile.
  {
    f32x4 acc[4];
    #pragma unroll
    for (int ts = 0; ts < 4; ++ts) acc[ts] = zz;
    #pragma unroll
    for (int ks = 0; ks < 8; ++ks) {
      bf16x8 af = *(const bf16x8*)(kb + (wv * 16 + l16) * KBLD + ks * 32 + quad * 8);
      #pragma unroll
      for (int ts = 0; ts < 4; ++ts) {
        bf16x8 bfv = *(const bf16x8*)(kb + (ts * 16 + l16) * KBLD + ks * 32 + quad * 8);
        acc[ts] = MFMA(af, bfv, acc[ts]);
      }
    }
    #pragma unroll
    for (int ts = 0; ts < 4; ++ts)
      #pragma unroll
      for (int r = 0; r < 4; ++r)
        r2[(wv * 16 + quad * 4 + r) * R2LD + ts * 16 + l16] = f2bf(acc[ts][r]);
  }
  // QK^T -> M (masked, decayed; odd rows only) directly to global
  {
    f32x4 acc[4];
    #pragma unroll
    for (int ts = 0; ts < 4; ++ts) acc[ts] = zz;
    int t_row = wv * 16 + l16;
    int podd = t_row & 1, iq = i0 + (t_row >> 1);
    const short* qrow = Qc + ((size_t)(b * 1024 + iq) * 6 + h) * 256;
    #pragma unroll
    for (int ks = 0; ks < 8; ++ks) {
      bf16x8 af = z8;
      if (podd) af = *(const bf16x8*)(qrow + ks * 32 + quad * 8);
      #pragma unroll
      for (int ts = 0; ts < 4; ++ts) {
        bf16x8 bfv = *(const bf16x8*)(kb + (ts * 16 + l16) * KBLD + ks * 32 + quad * 8);
        acc[ts] = MFMA(af, bfv, acc[ts]);
      }
    }
    short* Mp = Mm + idx * 2048;
    #pragma unroll
    for (int ts = 0; ts < 4; ++ts)
      #pragma unroll
      for (int r = 1; r < 4; r += 2) {       // odd rows only
        int t = wv * 16 + quad * 4 + r, s = ts * 16 + l16;
        float ct = __shfl(cum, t), cs = __shfl(cum, s);
        float v = (s <= t) ? acc[ts][r] * expf(ct - cs) : 0.f;
        Mp[(t >> 1) * 64 + s] = f2bf(v);
      }
  }
  // Qg (odd rows only): Qg[th][d] = exp(B_{2th+1}) q_{2th+1}[d]
  {
    int th = tid >> 3, dseg = (tid & 7) * 32;
    int t = th * 2 + 1;
    float sc = __shfl(eBt, t);
    const short* qrow = Qc + ((size_t)(b * 1024 + i0 + th) * 6 + h) * 256 + dseg;
    short* qgp = Qg + idx * 8192 + (size_t)th * 256 + dseg;
    #pragma unroll
    for (int e = 0; e < 32; e += 8) {
      bf16x8 v = *(const bf16x8*)(qrow + e);
      bf16x8 w;
      #pragma unroll
      for (int q2 = 0; q2 < 8; ++q2) w[q2] = f2bf(bf2f(v[q2]) * sc);
      *(bf16x8*)(qgp + e) = w;
    }
  }
  // KdT[d][t] = exp(B63-B_t) k_t[d]
  {
    int d = tid;
    short buf[64];
    #pragma unroll
    for (int t = 0; t < 64; ++t) {
      float sc = __shfl(eRem, t);
      buf[t] = f2bf(bf2f(kb[t * KBLD + d]) * sc);
    }
    short* kp = KdT + idx * 16384 + (size_t)d * 64;
    #pragma unroll
    for (int e = 0; e < 64; e += 8) {
      uint4 v; __builtin_memcpy(&v, buf + e, 16);
      *(uint4*)(kp + e) = v;
    }
  }
  __syncthreads();

  // C1: cache kb column d = tid in registers
  short colv[64];
  {
    int d = tid;
    #pragma unroll
    for (int t = 0; t < 64; ++t) colv[t] = kb[t * KBLD + d];
  }
  __syncthreads();
  // C2: wt[d][s] = beta_s exp(B_s) k_s[d] (over r0)
  {
    int d = tid;
    short wrow[64];
    #pragma unroll
    for (int s = 0; s < 64; ++s) wrow[s] = f2bf(bf2f(colv[s]) * __shfl(wsc, s));
    short* wp = r0 + d * WTLD;
    #pragma unroll
    for (int e = 0; e < 64; e += 8) {
      uint4 v; __builtin_memcpy(&v, wrow + e, 16);
      *(uint4*)(wp + e) = v;
    }
  }
  // C3: wave0 solves X = (I+A)^-1 by forward substitution (cols = lanes)
  if (wv == 0) {
    int j = lane;
    for (int t = 0; t < 64; ++t) {
      float bt = __shfl(betaL, t);
      float ct = __shfl(cum, t);
      float sacc = 0.f;
      for (int s = 0; s < t; ++s) {
        float cs = __shfl(cum, s);
        float a = bt * expf(ct - cs) * bf2f(r2[t * R2LD + s]);
        sacc += a * Xs[s * 64 + j];
      }
      Xs[t * 64 + j] = ((t == j) ? 1.f : 0.f) - sacc;
    }
  }
  __syncthreads();
  // X -> r2 (bf16)
  for (int e = tid; e < 4096; e += 256) {
    int t = e >> 6, s = e & 63;
    r2[t * R2LD + s] = f2bf(Xs[e]);
  }
  __syncthreads();
  // NTW = -(X @ W)
  {
    f32x4 acc[4][4];
    #pragma unroll
    for (int i = 0; i < 4; ++i)
      #pragma unroll
      for (int j = 0; j < 4; ++j) acc[i][j] = zz;
    #pragma unroll
    for (int ks = 0; ks < 2; ++ks) {
      bf16x8 af[4], bfv[4];
      #pragma unroll
      for (int tt = 0; tt < 4; ++tt)
        af[tt] = *(const bf16x8*)(r2 + (tt * 16 + l16) * R2LD + ks * 32 + quad * 8);
      #pragma unroll
      for (int dt = 0; dt < 4; ++dt)
        bfv[dt] = *(const bf16x8*)(r0 + ((wv * 4 + dt) * 16 + l16) * WTLD + ks * 32 + quad * 8);
      #pragma unroll
      for (int tt = 0; tt < 4; ++tt)
        #pragma unroll
        for (int dt = 0; dt < 4; ++dt)
          acc[tt][dt] = MFMA(af[tt], bfv[dt], acc[tt][dt]);
    }
    short* np = NTW + idx * 16384;
    #pragma unroll
    for (int tt = 0; tt < 4; ++tt)
      #pragma unroll
      for (int dt = 0; dt < 4; ++dt)
        #pragma unroll
        for (int r = 0; r < 4; ++r) {
          int t = tt * 16 + quad * 4 + r, d = (wv * 4 + dt) * 16 + l16;
          np[t * 256 + d] = f2bf(-acc[tt][dt][r]);
        }
  }
  __syncthreads();
  // TBV = X @ (beta*v), two DV halves through r0
  for (int vh = 0; vh < 2; ++vh) {
    {
      int vl = tid;
      short bv[64];
      #pragma unroll
      for (int t = 0; t < 64; ++t) {
        int par = t & 1, i = i0 + (t >> 1);
        const short* src = (par ? V1c : V0c) + (size_t)(b * 1024 + i) * 3072 + h * 512 + vh * 256 + vl;
        bv[t] = f2bf(bf2f(*src) * __shfl(betaL, t));
      }
      short* bp = r0 + vl * WTLD;
      #pragma unroll
      for (int e = 0; e < 64; e += 8) {
        uint4 v; __builtin_memcpy(&v, bv + e, 16);
        *(uint4*)(bp + e) = v;
      }
    }
    __syncthreads();
    {
      f32x4 acc[4][4];
      #pragma unroll
      for (int i = 0; i < 4; ++i)
        #pragma unroll
        for (int j = 0; j < 4; ++j) acc[i][j] = zz;
      #pragma unroll
      for (int ks = 0; ks < 2; ++ks) {
        bf16x8 af[4], bfv[4];
        #pragma unroll
        for (int tt = 0; tt < 4; ++tt)
          af[tt] = *(const bf16x8*)(r2 + (tt * 16 + l16) * R2LD + ks * 32 + quad * 8);
        #pragma unroll
        for (int vt = 0; vt < 4; ++vt)
          bfv[vt] = *(const bf16x8*)(r0 + ((wv * 4 + vt) * 16 + l16) * WTLD + ks * 32 + quad * 8);
        #pragma unroll
        for (int tt = 0; tt < 4; ++tt)
          #pragma unroll
          for (int vt = 0; vt < 4; ++vt)
            acc[tt][vt] = MFMA(af[tt], bfv[vt], acc[tt][vt]);
      }
      short* tp = TBV + idx * 32768;
      #pragma unroll
      for (int tt = 0; tt < 4; ++tt)
        #pragma unroll
        for (int vt = 0; vt < 4; ++vt)
          #pragma unroll
          for (int r = 0; r < 4; ++r) {
            int t = tt * 16 + quad * 4 + r, v = (wv * 4 + vt) * 16 + l16;
            tp[t * 512 + vh * 256 + v] = f2bf(acc[tt][vt][r]);
          }
    }
    __syncthreads();
  }
}

// ---------------------------------------------------------------------------
// Scan: 96 blocks x 4 waves. Wave w of block g handles (b,h)=g>>3,
// slice = (g&7)*4 + w. 4 waves read identical operand lines (L1 sharing).
#define SLD 264
#define ULD 72
__global__ __launch_bounds__(256) void scan_kernel(
    const short* __restrict__ NTW, const short* __restrict__ Qg,
    const short* __restrict__ KdT, const short* __restrict__ Mm,
    const short* __restrict__ TBV, const float* __restrict__ dC,
    short* __restrict__ O)
{
  __shared__ short Sall[4][16 * SLD];   // per-wave state slice [v_local][d]
  __shared__ short Uall[4][16 * ULD];   // per-wave u slice [v_local][t]
  int tid = threadIdx.x;
  int lane = tid & 63, w = tid >> 6;
  short* S = Sall[w];
  short* U = Uall[w];
  int quad = lane >> 4, l16 = lane & 15;
  int g = blockIdx.x;
  int bh = g >> 3, grp = g & 7;
  int slice = grp * 4 + w;
  int b = bh / 6, h = bh % 6;
  int vbase = slice * 16;
  f32x4 zz = {0.f, 0.f, 0.f, 0.f};
  for (int e = lane; e < 16 * SLD; e += 64) S[e] = 0;
  __syncthreads();

  for (int c = 0; c < 32; ++c) {
    size_t idx = (size_t)(bh * 32 + c);
    const short* ntw = NTW + idx * 16384;
    const short* qg  = Qg  + idx * 8192;
    const short* kdt = KdT + idx * 16384;
    const short* mp  = Mm  + idx * 2048;
    const short* tb  = TBV + idx * 32768;
    float dc = dC[idx];

    // u = NTW @ S0 + TBV
    f32x4 uac[4];
    #pragma unroll
    for (int tt = 0; tt < 4; ++tt)
      #pragma unroll
      for (int r = 0; r < 4; ++r)
        uac[tt][r] = bf2f(tb[(size_t)(tt * 16 + quad * 4 + r) * 512 + vbase + l16]);
    #pragma unroll
    for (int ks = 0; ks < 8; ++ks) {
      bf16x8 bfv = *(const bf16x8*)(S + l16 * SLD + ks * 32 + quad * 8);
      #pragma unroll
      for (int tt = 0; tt < 4; ++tt) {
        bf16x8 af = *(const bf16x8*)(ntw + (tt * 16 + l16) * 256 + ks * 32 + quad * 8);
        uac[tt] = MFMA(af, bfv, uac[tt]);
      }
    }
    #pragma unroll
    for (int tt = 0; tt < 4; ++tt)
      #pragma unroll
      for (int r = 0; r < 4; ++r)
        U[l16 * ULD + tt * 16 + quad * 4 + r] = f2bf(uac[tt][r]);
    __syncthreads();

    // o = Qg @ S0 + M @ u   (odd interleaved rows, 32 of them)
    f32x4 oac[2];
    #pragma unroll
    for (int tt = 0; tt < 2; ++tt) oac[tt] = zz;
    #pragma unroll
    for (int ks = 0; ks < 8; ++ks) {
      bf16x8 bfv = *(const bf16x8*)(S + l16 * SLD + ks * 32 + quad * 8);
      #pragma unroll
      for (int tt = 0; tt < 2; ++tt) {
        bf16x8 af = *(const bf16x8*)(qg + (tt * 16 + l16) * 256 + ks * 32 + quad * 8);
        oac[tt] = MFMA(af, bfv, oac[tt]);
      }
    }
    #pragma unroll
    for (int ks = 0; ks < 2; ++ks) {
      bf16x8 bfv = *(const bf16x8*)(U + l16 * ULD + ks * 32 + quad * 8);
      #pragma unroll
      for (int tt = 0; tt < 2; ++tt) {
        bf16x8 af = *(const bf16x8*)(mp + (tt * 16 + l16) * 64 + ks * 32 + quad * 8);
        oac[tt] = MFMA(af, bfv, oac[tt]);
      }
    }
    #pragma unroll
    for (int tt = 0; tt < 2; ++tt) {
      #pragma unroll
      for (int r = 0; r < 4; ++r) {
        int th = tt * 16 + quad * 4 + r;
        int i = c * 32 + th;
        O[((size_t)(b * 1024 + i) * 6 + h) * 512 + vbase + l16] = f2bf(oac[tt][r]);
      }
    }
    __syncthreads();

    // S1 = dc * S0 + KdT @ u
    #pragma unroll
    for (int g2 = 0; g2 < 4; ++g2) {
      f32x4 sac[4];
      #pragma unroll
      for (int dt = 0; dt < 4; ++dt)
        #pragma unroll
        for (int r = 0; r < 4; ++r)
          sac[dt][r] = dc * bf2f(S[l16 * SLD + (g2 * 4 + dt) * 16 + quad * 4 + r]);
      #pragma unroll
      for (int ks = 0; ks < 2; ++ks) {
        bf16x8 bfv = *(const bf16x8*)(U + l16 * ULD + ks * 32 + quad * 8);
        #pragma unroll
        for (int dt = 0; dt < 4; ++dt) {
          bf16x8 af = *(const bf16x8*)(kdt + ((g2 * 4 + dt) * 16 + l16) * 64 + ks * 32 + quad * 8);
          sac[dt] = MFMA(af, bfv, sac[dt]);
        }
      }
      #pragma unroll
      for (int dt = 0; dt < 4; ++dt)
        #pragma unroll
        for (int r = 0; r < 4; ++r)
          S[l16 * SLD + (g2 * 4 + dt) * 16 + quad * 4 + r] = f2bf(sac[dt][r]);
    }
    __syncthreads();
  }
}

// ---------------------------------------------------------------------------
// RMS-norm over DV per (b,t,h), times silu(gate). grid (2048, 6).
__global__ __launch_bounds__(256) void rms_gate(
    const short* __restrict__ O, const short* __restrict__ P,
    const float* __restrict__ onw, short* __restrict__ OutPre)
{
  __shared__ float red[256];
  int tid = threadIdx.x, h = blockIdx.y, row = blockIdx.x;
  size_t base = ((size_t)row * 6 + h) * 512;
  float a = bf2f(O[base + tid]), b2 = bf2f(O[base + 256 + tid]);
  red[tid] = a * a + b2 * b2;
  __syncthreads();
  for (int s = 128; s > 0; s >>= 1) {
    if (tid < s) red[tid] += red[tid + s];
    __syncthreads();
  }
  float r = rsqrtf(red[0] * (1.f / 512.f) + 1e-5f);
  #pragma unroll
  for (int half = 0; half < 2; ++half) {
    int col = tid + half * 256;
    float ov = half ? b2 : a;
    float g = bf2f(P[(size_t)row * PJ_N + 10752 + h * 512 + col]);
    float sg = g / (1.f + expf(-g));
    OutPre[(size_t)row * 3072 + h * 512 + col] = f2bf(ov * r * onw[col] * sg);
  }
}

// ---------------------------------------------------------------------------
extern "C" void kernel_launch(void* const* d_in, const int* in_sizes, int n_in,
                              void* d_out, int out_size, void* d_ws, size_t ws_size,
                              hipStream_t stream) {
  const float* x        = (const float*)d_in[0];
  const float* q_w      = (const float*)d_in[1];
  const float* k_ws     = (const float*)d_in[2];
  const float* v_ws     = (const float*)d_in[3];
  const float* b_ws     = (const float*)d_in[4];
  const float* a_w      = (const float*)d_in[5];
  const float* g_w      = (const float*)d_in[6];
  const float* o_w      = (const float*)d_in[7];
  const float* q_conv_w = (const float*)d_in[8];
  const float* k_conv   = (const float*)d_in[9];
  const float* v_conv   = (const float*)d_in[10];
  const float* A_log    = (const float*)d_in[11];
  const float* dt_bias  = (const float*)d_in[12];
  const float* o_norm_w = (const float*)d_in[13];
  float* out = (float*)d_out;

  char* ws = (char*)d_ws;
  size_t off = 0;
  auto take = [&](size_t bytes) {
    size_t r = off;
    off += (bytes + 255) & ~(size_t)255;
    return r;
  };
  // Persistent buffers
  short* P  = (short*)(ws + take((size_t)NTOK * PJ_N * 2));   // live 3-8
  short* oT = (short*)(ws + take((size_t)2048 * 3072 * 2));   // live 2-9
  // xbf (step 3 only) reused for Mm (steps 6-7)
  size_t regX = take((size_t)NTOK * 2048 * 2);                // 8.39 MB
  short* xbf = (short*)(ws + regX);
  short* Mm  = (short*)(ws + regX);                           // 1.57 MB
  // Region A: WTall (steps 2-3) reused for NTW|Qg|KdT|TBV (steps 6-7)
  size_t regA = take((size_t)PJ_N * 2048 * 2);                // 56,623,104 B
  short* WTall = (short*)(ws + regA);
  short* NTW = (short*)(ws + regA);
  short* Qg  = NTW + (size_t)384 * 16384;
  short* KdT = Qg  + (size_t)384 * 8192;
  short* TBV = KdT + (size_t)384 * 16384;   // ends exactly at regA + 56,623,104
  // Region B: conv outputs (steps 5-6) reused for O/OutPre (steps 7-9)
  size_t regB = take((size_t)44040192);                       // 44.0 MB
  short* Qc  = (short*)(ws + regB);
  short* K0c = Qc  + (size_t)NTOK * 1536;
  short* K1c = K0c + (size_t)NTOK * 1536;
  short* V0c = K1c + (size_t)NTOK * 1536;
  short* V1c = V0c + (size_t)NTOK * 3072;
  short* O      = (short*)(ws + regB);                        // 12.6 MB
  short* OutPre = O + (size_t)NTOK * 6 * 512;                 // 12.6 MB
  float* Beta0 = (float*)(ws + take((size_t)NTOK * 6 * 4));
  float* Beta1 = (float*)(ws + take((size_t)NTOK * 6 * 4));
  float* G     = (float*)(ws + take((size_t)NTOK * 6 * 4));
  float* dCp   = (float*)(ws + take((size_t)384 * 4));
  if (off > ws_size) return;  // ws too small: no-op (diagnosable, capture-safe)

  // 1) convert x to bf16
  cvt_bf16<<<dim3(NTOK * 2048 / 8 / 256), 256, 0, stream>>>(x, xbf, NTOK * 2048);

  // 2) weight transposes (fp32 -> bf16) into WTall [q|k0|k1|v0|v1|gate] and oT
  transpose_w<<<dim3(24), 256, 0, stream>>>(q_w, WTall, 2048, 1536);
  transpose_w<<<dim3(24), 256, 0, stream>>>(k_ws, WTall + (size_t)1536 * 2048, 2048, 1536);
  transpose_w<<<dim3(24), 256, 0, stream>>>(k_ws + (size_t)2048 * 1536, WTall + (size_t)3072 * 2048, 2048, 1536);
  transpose_w<<<dim3(48), 256, 0, stream>>>(v_ws, WTall + (size_t)4608 * 2048, 2048, 3072);
  transpose_w<<<dim3(48), 256, 0, stream>>>(v_ws + (size_t)2048 * 3072, WTall + (size_t)7680 * 2048, 2048, 3072);
  transpose_w<<<dim3(48), 256, 0, stream>>>(g_w, WTall + (size_t)10752 * 2048, 2048, 3072);
  transpose_w<<<dim3(32), 256, 0, stream>>>(o_w, oT, 3072, 2048);

  // 3) fused projection GEMM (XCD-aware 1-D grid, N padded 108->112 tiles)
  gemm_bt<false><<<dim3(16 * 112), 256, 0, stream>>>(
      xbf, WTall, P, NTOK, PJ_N, 2048);

  // 4) beta / g (fp32 inputs straight from d_in)
  proj_small<<<dim3(NTOK), 64, 0, stream>>>(x, b_ws, a_w, A_log, dt_bias, Beta0, Beta1, G);

  // 5) conv + silu (+ l2norm for q/k)
  conv_norm_qk<<<dim3(NTOK, 6), 256, 0, stream>>>(P, q_conv_w, Qc, 0, 0.0625f);
  conv_norm_qk<<<dim3(NTOK, 6), 256, 0, stream>>>(P, k_conv, K0c, 1536, 1.f);
  conv_norm_qk<<<dim3(NTOK, 6), 256, 0, stream>>>(P, k_conv + (size_t)1536 * 4, K1c, 3072, 1.f);
  conv_v<<<dim3(NTOK, 12), 256, 0, stream>>>(P, v_conv, V0c, 4608);
  conv_v<<<dim3(NTOK, 12), 256, 0, stream>>>(P, v_conv + (size_t)3072 * 4, V1c, 7680);

  // 6) chunk operand precompute (WY form)
  precompute_chunk<<<dim3(32, 6, 2), 256, 0, stream>>>(Qc, K0c, K1c, V0c, V1c,
      Beta0, Beta1, G, NTW, Qg, KdT, Mm, TBV, dCp);

  // 7) sequential chunk scan (96 blocks x 4 waves, L1 operand sharing)
  scan_kernel<<<dim3(96), 256, 0, stream>>>(NTW, Qg, KdT, Mm, TBV, dCp, O);

  // 8) rms-norm * silu(gate)
  rms_gate<<<dim3(NTOK, 6), 256, 0, stream>>>(O, P, o_norm_w, OutPre);

  // 9) output projection (fp32 out; 16 N-tiles, no padding needed)
  gemm_bt<true><<<dim3(16 * 16), 256, 0, stream>>>(
      OutPre, oT, out, NTOK, 2048, 3072);
}

// Round 8
// 1418.605 us; speedup vs baseline: 3.1215x; 1.2818x over previous
//
#include <hip/hip_runtime.h>

// ---------------------------------------------------------------------------
// GatedDeltaProduct: B=2,T=1024,HID=2048, NH=2, H=6, DK=256, DV=512, CHUNK=64
// Inputs fp32, output fp32. Internal bf16 MFMA. WY chunked gated delta rule.
// R8: scan = single-wave blocks, LDS-staged NTW/Qg (global_load_lds + XOR
//     swizzle), KdT/Mm/TBV register-prefetched, zero barriers.
// ---------------------------------------------------------------------------

typedef short bf16x8 __attribute__((ext_vector_type(8)));
typedef float f32x4 __attribute__((ext_vector_type(4)));

__device__ __forceinline__ float bf2f(short s) {
  unsigned u = ((unsigned)(unsigned short)s) << 16;
  float f; __builtin_memcpy(&f, &u, 4); return f;
}
__device__ __forceinline__ short f2bf(float f) {
  unsigned u; __builtin_memcpy(&u, &f, 4);
  u = (u + 0x7FFFu + ((u >> 16) & 1u)) >> 16;
  return (short)u;
}
__device__ __forceinline__ f32x4 MFMA(bf16x8 a, bf16x8 b, f32x4 c) {
  return __builtin_amdgcn_mfma_f32_16x16x32_bf16(a, b, c, 0, 0, 0);
}
// async global->LDS, 16B per lane; lds dest = wave-uniform base + lane*16
__device__ __forceinline__ void gl_lds16(const short* g, short* l) {
  __builtin_amdgcn_global_load_lds(
      (const __attribute__((address_space(1))) unsigned int*)g,
      (__attribute__((address_space(3))) unsigned int*)l, 16, 0, 0);
}

#define PJ_N 13824   // [q 0:1536][k0][k1][v0 4608:][v1 7680:][gate 10752:]
#define NTOK 2048    // B*T rows

// ---------------------------------------------------------------------------
// fp32 -> bf16 bulk convert (for x). n multiple of 8.
__global__ __launch_bounds__(256) void cvt_bf16(
    const float* __restrict__ src, short* __restrict__ dst, int n)
{
  int i = (blockIdx.x * 256 + threadIdx.x) * 8;
  if (i + 8 <= n) {
    float4 a = *(const float4*)(src + i);
    float4 b = *(const float4*)(src + i + 4);
    short v[8] = {f2bf(a.x), f2bf(a.y), f2bf(a.z), f2bf(a.w),
                  f2bf(b.x), f2bf(b.y), f2bf(b.z), f2bf(b.w)};
    uint4 u; __builtin_memcpy(&u, v, 16);
    *(uint4*)(dst + i) = u;
  }
}

// ---------------------------------------------------------------------------
// Weight transpose + convert: W (K x N, fp32) -> WT (N x K, bf16).
__global__ __launch_bounds__(256) void transpose_w(
    const float* __restrict__ W, short* __restrict__ WT, int K, int N)
{
  int lane = threadIdx.x & 63, y = threadIdx.x >> 6;
  int n = blockIdx.x * 64 + lane;
  for (int k0 = y * 8; k0 < K; k0 += 32) {
    short v[8];
    #pragma unroll
    for (int j = 0; j < 8; ++j) v[j] = f2bf(W[(size_t)(k0 + j) * N + n]);
    uint4 u; __builtin_memcpy(&u, v, 16);
    *(uint4*)(WT + (size_t)n * K + k0) = u;
  }
}

// ---------------------------------------------------------------------------
// GEMM: C[M,N] = A[M,K] @ B, given BT (N x K). bf16 in, fp32 accum.
// 1-D grid, XCD-aware. global_load_lds staging, XOR-swizzled LDS.
template<bool F32OUT>
__global__ __launch_bounds__(256) void gemm_bt(
    const short* __restrict__ A, const short* __restrict__ BT,
    void* __restrict__ Cp, int M, int N, int K)
{
  __shared__ short As[128 * 64];
  __shared__ short Bs[128 * 64];
  const int tid = threadIdx.x;
  const int lane = tid & 63, wv = tid >> 6;
  const int quad = lane >> 4, l16 = lane & 15;
  const int j = blockIdx.x;
  const int xcd = j & 7, local = j >> 3;
  const int mtile = local & 15, ng = local >> 4;
  const int ntile = ng * 8 + xcd;
  if (ntile * 128 >= N) return;     // pad blocks no-op (uniform per block)
  const int m0 = mtile * 128, n0 = ntile * 128;
  const int wm = (wv >> 1) * 64, wn = (wv & 1) * 64;
  const int lrow = lane >> 3;              // 0..7 within staging call
  const int lperm = (lane & 7) ^ lrow;     // xor swizzle source segment
  const int xr = l16 & 7;                  // read-side xor key
  f32x4 zz = {0.f, 0.f, 0.f, 0.f};
  f32x4 acc[4][4];
  #pragma unroll
  for (int i = 0; i < 4; ++i)
    #pragma unroll
    for (int jj = 0; jj < 4; ++jj) acc[i][jj] = zz;

  for (int k0 = 0; k0 < K; k0 += 64) {
    __syncthreads();
    #pragma unroll
    for (int c = 0; c < 4; ++c) {
      int row = (wv * 4 + c) * 8 + lrow;
      gl_lds16(A  + (size_t)(m0 + row) * K + k0 + lperm * 8,
               As + (wv * 4 + c) * 512);
      gl_lds16(BT + (size_t)(n0 + row) * K + k0 + lperm * 8,
               Bs + (wv * 4 + c) * 512);
    }
    __syncthreads();
    #pragma unroll
    for (int kk = 0; kk < 64; kk += 32) {
      const int ksb = kk >> 3;
      bf16x8 af[4], bfr[4];
      #pragma unroll
      for (int i = 0; i < 4; ++i)
        af[i] = *(const bf16x8*)(As + (wm + i * 16 + l16) * 64 +
                                 (((ksb + quad) ^ xr) << 3));
      #pragma unroll
      for (int jj = 0; jj < 4; ++jj)
        bfr[jj] = *(const bf16x8*)(Bs + (wn + jj * 16 + l16) * 64 +
                                   (((ksb + quad) ^ xr) << 3));
      #pragma unroll
      for (int i = 0; i < 4; ++i)
        #pragma unroll
        for (int jj = 0; jj < 4; ++jj)
          acc[i][jj] = MFMA(af[i], bfr[jj], acc[i][jj]);
    }
  }
  #pragma unroll
  for (int i = 0; i < 4; ++i)
    #pragma unroll
    for (int jj = 0; jj < 4; ++jj)
      #pragma unroll
      for (int r = 0; r < 4; ++r) {
        int row = m0 + wm + i * 16 + quad * 4 + r;
        int col = n0 + wn + jj * 16 + l16;
        if (F32OUT) ((float*)Cp)[(size_t)row * N + col] = acc[i][jj][r];
        else        ((short*)Cp)[(size_t)row * N + col] = f2bf(acc[i][jj][r]);
      }
}

// ---------------------------------------------------------------------------
// beta (sigmoid(x@b_ws[i])) and g (-exp(A_log)*softplus(x@a_w+dt_bias)).
__global__ __launch_bounds__(64) void proj_small(
    const float* __restrict__ x, const float* __restrict__ b_ws,
    const float* __restrict__ a_w, const float* __restrict__ A_log,
    const float* __restrict__ dt_bias,
    float* __restrict__ Beta0, float* __restrict__ Beta1, float* __restrict__ G)
{
  int row = blockIdx.x, lane = threadIdx.x;
  float p[18];
  #pragma unroll
  for (int j = 0; j < 18; ++j) p[j] = 0.f;
  for (int k = lane; k < 2048; k += 64) {
    float xv = x[(size_t)row * 2048 + k];
    const float* b0 = b_ws + (size_t)k * 6;
    const float* b1 = b_ws + (size_t)2048 * 6 + (size_t)k * 6;
    const float* aw = a_w + (size_t)k * 6;
    #pragma unroll
    for (int j = 0; j < 6; ++j) {
      p[j]      += xv * b0[j];
      p[6 + j]  += xv * b1[j];
      p[12 + j] += xv * aw[j];
    }
  }
  #pragma unroll
  for (int j = 0; j < 18; ++j) {
    #pragma unroll
    for (int off = 32; off > 0; off >>= 1)
      p[j] += __shfl_down(p[j], off);
  }
  if (lane == 0) {
    #pragma unroll
    for (int j = 0; j < 6; ++j) {
      Beta0[(size_t)row * 6 + j] = 1.f / (1.f + expf(-p[j]));
      Beta1[(size_t)row * 6 + j] = 1.f / (1.f + expf(-p[6 + j]));
      float z = p[12 + j] + dt_bias[j];
      float sp = (z > 15.f) ? z : log1pf(expf(z));
      G[(size_t)row * 6 + j] = -expf(A_log[j]) * sp;
    }
  }
}

// ---------------------------------------------------------------------------
// Conv(K=4 causal, depthwise) + SiLU + per-head l2norm (q/k). grid (2048, 6).
__global__ __launch_bounds__(256) void conv_norm_qk(
    const short* __restrict__ P, const float* __restrict__ convw,
    short* __restrict__ dst, int colofs, float scale)
{
  __shared__ float red[256];
  int c = threadIdx.x, h = blockIdx.y, row = blockIdx.x;
  int t = row & 1023;
  int ch = colofs + h * 256 + c;
  const float* cw = convw + (size_t)(h * 256 + c) * 4;
  float acc = 0.f;
  #pragma unroll
  for (int j = 0; j < 4; ++j) {
    int tt = t - 3 + j;
    if (tt >= 0) acc += bf2f(P[(size_t)(row - 3 + j) * PJ_N + ch]) * cw[j];
  }
  float y = acc / (1.f + expf(-acc));   // silu
  red[c] = y * y;
  __syncthreads();
  for (int s = 128; s > 0; s >>= 1) {
    if (c < s) red[c] += red[c + s];
    __syncthreads();
  }
  float nrm = rsqrtf(red[0] + 1e-12f) * scale;
  dst[((size_t)row * 6 + h) * 256 + c] = f2bf(y * nrm);
}

// Conv + SiLU for v. grid (2048, 12).
__global__ __launch_bounds__(256) void conv_v(
    const short* __restrict__ P, const float* __restrict__ convw,
    short* __restrict__ dst, int colofs)
{
  int cg = blockIdx.y * 256 + threadIdx.x;
  int row = blockIdx.x;
  int t = row & 1023;
  const float* cw = convw + (size_t)cg * 4;
  float acc = 0.f;
  #pragma unroll
  for (int j = 0; j < 4; ++j) {
    int tt = t - 3 + j;
    if (tt >= 0) acc += bf2f(P[(size_t)(row - 3 + j) * PJ_N + colofs + cg]) * cw[j];
  }
  float y = acc / (1.f + expf(-acc));
  dst[(size_t)row * 3072 + cg] = f2bf(y);
}

// ---------------------------------------------------------------------------
// Per-(b,h,chunk) precompute of WY operands. grid (32, 6, 2), block 256.
// Qg/Mm store only odd interleaved rows (32 per chunk).
#define KBLD 264
#define R2LD 72
#define WTLD 72
__global__ __launch_bounds__(256) void precompute_chunk(
    const short* __restrict__ Qc, const short* __restrict__ K0c, const short* __restrict__ K1c,
    const short* __restrict__ V0c, const short* __restrict__ V1c,
    const float* __restrict__ Beta0, const float* __restrict__ Beta1, const float* __restrict__ G,
    short* __restrict__ NTW, short* __restrict__ Qg, short* __restrict__ KdT,
    short* __restrict__ Mm, short* __restrict__ TBV, float* __restrict__ dC)
{
  __shared__ short r0[256 * 72];   // kb (64 x KBLD) -> wt (256 x WTLD) -> BVT
  __shared__ float Xs[64 * 64];    // (I+A)^-1 (f32)
  __shared__ short r2[64 * 72];    // KK^T (bf16) -> X (bf16)
  const int tid = threadIdx.x;
  const int lane = tid & 63, wv = tid >> 6;
  const int quad = lane >> 4, l16 = lane & 15;
  const int c = blockIdx.x, h = blockIdx.y, b = blockIdx.z;
  const int i0 = c * 32;
  const size_t idx = (size_t)((b * 6 + h) * 32 + c);
  short* kb = r0;
  f32x4 zz = {0.f, 0.f, 0.f, 0.f};
  bf16x8 z8 = {0, 0, 0, 0, 0, 0, 0, 0};

  // per-lane g/beta for interleaved position t = lane; wave-prefix cumsum
  float gv, betaL;
  {
    int t = lane, par = t & 1, i = i0 + (t >> 1);
    size_t gofs = (size_t)(b * 1024 + i) * 6 + h;
    gv = par ? 0.f : G[gofs];
    betaL = par ? Beta1[gofs] : Beta0[gofs];
  }
  float cum = gv;
  #pragma unroll
  for (int off = 1; off < 64; off <<= 1) {
    float nb = __shfl_up(cum, off);
    if (lane >= off) cum += nb;
  }
  float c63 = __shfl(cum, 63);
  float eBt = expf(cum);          // exp(B_t)
  float eRem = expf(c63 - cum);   // exp(B63 - B_t)
  float wsc = betaL * eBt;        // beta_t exp(B_t)
  if (tid == 0) dC[idx] = expf(c63);

  // stage k chunk (interleaved parities) into kb
  {
    int row = tid >> 2, seg = (tid & 3) * 64;
    int par = row & 1, i = i0 + (row >> 1);
    const short* src = (par ? K1c : K0c) + ((size_t)(b * 1024 + i) * 6 + h) * 256 + seg;
    short* dp = kb + row * KBLD + seg;
    #pragma unroll
    for (int e = 0; e < 64; e += 8)
      *(uint4*)(dp + e) = *(const uint4*)(src + e);
  }
  __syncthreads();

  // KK^T (bf16 into r2). wave = t row-tile.
  {
    f32x4 acc[4];
    #pragma unroll
    for (int ts = 0; ts < 4; ++ts) acc[ts] = zz;
    #pragma unroll
    for (int ks = 0; ks < 8; ++ks) {
      bf16x8 af = *(const bf16x8*)(kb + (wv * 16 + l16) * KBLD + ks * 32 + quad * 8);
      #pragma unroll
      for (int ts = 0; ts < 4; ++ts) {
        bf16x8 bfv = *(const bf16x8*)(kb + (ts * 16 + l16) * KBLD + ks * 32 + quad * 8);
        acc[ts] = MFMA(af, bfv, acc[ts]);
      }
    }
    #pragma unroll
    for (int ts = 0; ts < 4; ++ts)
      #pragma unroll
      for (int r = 0; r < 4; ++r)
        r2[(wv * 16 + quad * 4 + r) * R2LD + ts * 16 + l16] = f2bf(acc[ts][r]);
  }
  // QK^T -> M (masked, decayed; odd rows only) directly to global
  {
    f32x4 acc[4];
    #pragma unroll
    for (int ts = 0; ts < 4; ++ts) acc[ts] = zz;
    int t_row = wv * 16 + l16;
    int podd = t_row & 1, iq = i0 + (t_row >> 1);
    const short* qrow = Qc + ((size_t)(b * 1024 + iq) * 6 + h) * 256;
    #pragma unroll
    for (int ks = 0; ks < 8; ++ks) {
      bf16x8 af = z8;
      if (podd) af = *(const bf16x8*)(qrow + ks * 32 + quad * 8);
      #pragma unroll
      for (int ts = 0; ts < 4; ++ts) {
        bf16x8 bfv = *(const bf16x8*)(kb + (ts * 16 + l16) * KBLD + ks * 32 + quad * 8);
        acc[ts] = MFMA(af, bfv, acc[ts]);
      }
    }
    short* Mp = Mm + idx * 2048;
    #pragma unroll
    for (int ts = 0; ts < 4; ++ts)
      #pragma unroll
      for (int r = 1; r < 4; r += 2) {       // odd rows only
        int t = wv * 16 + quad * 4 + r, s = ts * 16 + l16;
        float ct = __shfl(cum, t), cs = __shfl(cum, s);
        float v = (s <= t) ? acc[ts][r] * expf(ct - cs) : 0.f;
        Mp[(t >> 1) * 64 + s] = f2bf(v);
      }
  }
  // Qg (odd rows only): Qg[th][d] = exp(B_{2th+1}) q_{2th+1}[d]
  {
    int th = tid >> 3, dseg = (tid & 7) * 32;
    int t = th * 2 + 1;
    float sc = __shfl(eBt, t);
    const short* qrow = Qc + ((size_t)(b * 1024 + i0 + th) * 6 + h) * 256 + dseg;
    short* qgp = Qg + idx * 8192 + (size_t)th * 256 + dseg;
    #pragma unroll
    for (int e = 0; e < 32; e += 8) {
      bf16x8 v = *(const bf16x8*)(qrow + e);
      bf16x8 w;
      #pragma unroll
      for (int q2 = 0; q2 < 8; ++q2) w[q2] = f2bf(bf2f(v[q2]) * sc);
      *(bf16x8*)(qgp + e) = w;
    }
  }
  // KdT[d][t] = exp(B63-B_t) k_t[d]
  {
    int d = tid;
    short buf[64];
    #pragma unroll
    for (int t = 0; t < 64; ++t) {
      float sc = __shfl(eRem, t);
      buf[t] = f2bf(bf2f(kb[t * KBLD + d]) * sc);
    }
    short* kp = KdT + idx * 16384 + (size_t)d * 64;
    #pragma unroll
    for (int e = 0; e < 64; e += 8) {
      uint4 v; __builtin_memcpy(&v, buf + e, 16);
      *(uint4*)(kp + e) = v;
    }
  }
  __syncthreads();

  // C1: cache kb column d = tid in registers
  short colv[64];
  {
    int d = tid;
    #pragma unroll
    for (int t = 0; t < 64; ++t) colv[t] = kb[t * KBLD + d];
  }
  __syncthreads();
  // C2: wt[d][s] = beta_s exp(B_s) k_s[d] (over r0)
  {
    int d = tid;
    short wrow[64];
    #pragma unroll
    for (int s = 0; s < 64; ++s) wrow[s] = f2bf(bf2f(colv[s]) * __shfl(wsc, s));
    short* wp = r0 + d * WTLD;
    #pragma unroll
    for (int e = 0; e < 64; e += 8) {
      uint4 v; __builtin_memcpy(&v, wrow + e, 16);
      *(uint4*)(wp + e) = v;
    }
  }
  // C3: wave0 solves X = (I+A)^-1 by forward substitution (cols = lanes)
  if (wv == 0) {
    int j = lane;
    for (int t = 0; t < 64; ++t) {
      float bt = __shfl(betaL, t);
      float ct = __shfl(cum, t);
      float sacc = 0.f;
      for (int s = 0; s < t; ++s) {
        float cs = __shfl(cum, s);
        float a = bt * expf(ct - cs) * bf2f(r2[t * R2LD + s]);
        sacc += a * Xs[s * 64 + j];
      }
      Xs[t * 64 + j] = ((t == j) ? 1.f : 0.f) - sacc;
    }
  }
  __syncthreads();
  // X -> r2 (bf16)
  for (int e = tid; e < 4096; e += 256) {
    int t = e >> 6, s = e & 63;
    r2[t * R2LD + s] = f2bf(Xs[e]);
  }
  __syncthreads();
  // NTW = -(X @ W)
  {
    f32x4 acc[4][4];
    #pragma unroll
    for (int i = 0; i < 4; ++i)
      #pragma unroll
      for (int j = 0; j < 4; ++j) acc[i][j] = zz;
    #pragma unroll
    for (int ks = 0; ks < 2; ++ks) {
      bf16x8 af[4], bfv[4];
      #pragma unroll
      for (int tt = 0; tt < 4; ++tt)
        af[tt] = *(const bf16x8*)(r2 + (tt * 16 + l16) * R2LD + ks * 32 + quad * 8);
      #pragma unroll
      for (int dt = 0; dt < 4; ++dt)
        bfv[dt] = *(const bf16x8*)(r0 + ((wv * 4 + dt) * 16 + l16) * WTLD + ks * 32 + quad * 8);
      #pragma unroll
      for (int tt = 0; tt < 4; ++tt)
        #pragma unroll
        for (int dt = 0; dt < 4; ++dt)
          acc[tt][dt] = MFMA(af[tt], bfv[dt], acc[tt][dt]);
    }
    short* np = NTW + idx * 16384;
    #pragma unroll
    for (int tt = 0; tt < 4; ++tt)
      #pragma unroll
      for (int dt = 0; dt < 4; ++dt)
        #pragma unroll
        for (int r = 0; r < 4; ++r) {
          int t = tt * 16 + quad * 4 + r, d = (wv * 4 + dt) * 16 + l16;
          np[t * 256 + d] = f2bf(-acc[tt][dt][r]);
        }
  }
  __syncthreads();
  // TBV = X @ (beta*v), two DV halves through r0
  for (int vh = 0; vh < 2; ++vh) {
    {
      int vl = tid;
      short bv[64];
      #pragma unroll
      for (int t = 0; t < 64; ++t) {
        int par = t & 1, i = i0 + (t >> 1);
        const short* src = (par ? V1c : V0c) + (size_t)(b * 1024 + i) * 3072 + h * 512 + vh * 256 + vl;
        bv[t] = f2bf(bf2f(*src) * __shfl(betaL, t));
      }
      short* bp = r0 + vl * WTLD;
      #pragma unroll
      for (int e = 0; e < 64; e += 8) {
        uint4 v; __builtin_memcpy(&v, bv + e, 16);
        *(uint4*)(bp + e) = v;
      }
    }
    __syncthreads();
    {
      f32x4 acc[4][4];
      #pragma unroll
      for (int i = 0; i < 4; ++i)
        #pragma unroll
        for (int j = 0; j < 4; ++j) acc[i][j] = zz;
      #pragma unroll
      for (int ks = 0; ks < 2; ++ks) {
        bf16x8 af[4], bfv[4];
        #pragma unroll
        for (int tt = 0; tt < 4; ++tt)
          af[tt] = *(const bf16x8*)(r2 + (tt * 16 + l16) * R2LD + ks * 32 + quad * 8);
        #pragma unroll
        for (int vt = 0; vt < 4; ++vt)
          bfv[vt] = *(const bf16x8*)(r0 + ((wv * 4 + vt) * 16 + l16) * WTLD + ks * 32 + quad * 8);
        #pragma unroll
        for (int tt = 0; tt < 4; ++tt)
          #pragma unroll
          for (int vt = 0; vt < 4; ++vt)
            acc[tt][vt] = MFMA(af[tt], bfv[vt], acc[tt][vt]);
      }
      short* tp = TBV + idx * 32768;
      #pragma unroll
      for (int tt = 0; tt < 4; ++tt)
        #pragma unroll
        for (int vt = 0; vt < 4; ++vt)
          #pragma unroll
          for (int r = 0; r < 4; ++r) {
            int t = tt * 16 + quad * 4 + r, v = (wv * 4 + vt) * 16 + l16;
            tp[t * 512 + vh * 256 + v] = f2bf(acc[tt][vt][r]);
          }
    }
    __syncthreads();
  }
}

// ---------------------------------------------------------------------------
// Scan: one wave per (b,h,16-col DV slice). grid 384, block 64, no barriers.
// NTW/Qg staged to LDS per chunk via global_load_lds with XOR-seg swizzle;
// KdT (128 VGPRs, two halves), Mm, TBV register-prefetched.
#define SLD 264
#define ULD 72
__global__ __launch_bounds__(64) void scan_kernel(
    const short* __restrict__ NTW, const short* __restrict__ Qg,
    const short* __restrict__ KdT, const short* __restrict__ Mm,
    const short* __restrict__ TBV, const float* __restrict__ dC,
    short* __restrict__ O)
{
  __shared__ short NTWs[64 * 256];  // 32KB, LDS[t][s] = G[t][s ^ (t&7)]
  __shared__ short Qgs[32 * 256];   // 16KB, same swizzle
  __shared__ short S[16 * SLD];     // state slice [v_local][d], bf16
  __shared__ short U[16 * ULD];     // u slice [v_local][t], bf16
  const int lane = threadIdx.x;
  const int quad = lane >> 4, l16 = lane & 15;
  const int xk = l16 & 7;           // read-side xor key (row&7 == l16&7)
  const int r2l = lane >> 5;        // staging: row within pair
  const int s32 = lane & 31;        // staging: seg 0..31
  const int bh = blockIdx.x >> 5, slice = blockIdx.x & 31;
  const int b = bh / 6, h = bh % 6;
  const int vbase = slice * 16;
  f32x4 zz = {0.f, 0.f, 0.f, 0.f};
  for (int e = lane; e < 16 * SLD; e += 64) S[e] = 0;

  for (int c = 0; c < 32; ++c) {
    size_t idx = (size_t)(bh * 32 + c);
    const short* ntw = NTW + idx * 16384;
    const short* qg  = Qg  + idx * 8192;
    const short* kdt = KdT + idx * 16384;
    const short* mp  = Mm  + idx * 2048;
    const short* tb  = TBV + idx * 32768;
    float dc = dC[idx];

    // --- prefetch regs: Mm, TBV, KdT half A (g2 = 0,1) ---
    bf16x8 mmr[2][2];
    #pragma unroll
    for (int ks = 0; ks < 2; ++ks)
      #pragma unroll
      for (int tt = 0; tt < 2; ++tt)
        mmr[ks][tt] = *(const bf16x8*)(mp + (tt * 16 + l16) * 64 + ks * 32 + quad * 8);
    float tbr[4][4];
    #pragma unroll
    for (int tt = 0; tt < 4; ++tt)
      #pragma unroll
      for (int r = 0; r < 4; ++r)
        tbr[tt][r] = bf2f(tb[(size_t)(tt * 16 + quad * 4 + r) * 512 + vbase + l16]);
    bf16x8 kdA[2][2][4];
    #pragma unroll
    for (int g2 = 0; g2 < 2; ++g2)
      #pragma unroll
      for (int ks = 0; ks < 2; ++ks)
        #pragma unroll
        for (int dt = 0; dt < 4; ++dt)
          kdA[g2][ks][dt] = *(const bf16x8*)(kdt + ((g2 * 4 + dt) * 16 + l16) * 64 + ks * 32 + quad * 8);

    // --- stage NTW (32 calls) + Qg (16 calls) into LDS, swizzled ---
    #pragma unroll
    for (int j2 = 0; j2 < 32; ++j2) {
      int row = j2 * 2 + r2l;
      gl_lds16(ntw + row * 256 + ((s32 ^ (row & 7)) << 3), NTWs + j2 * 512);
    }
    #pragma unroll
    for (int j2 = 0; j2 < 16; ++j2) {
      int row = j2 * 2 + r2l;
      gl_lds16(qg + row * 256 + ((s32 ^ (row & 7)) << 3), Qgs + j2 * 512);
    }
    __builtin_amdgcn_s_waitcnt(0);   // drain staging + reg prefetch

    // --- u = NTW @ S0 + TBV ---
    f32x4 uac[4];
    #pragma unroll
    for (int tt = 0; tt < 4; ++tt)
      #pragma unroll
      for (int r = 0; r < 4; ++r)
        uac[tt][r] = tbr[tt][r];
    #pragma unroll
    for (int ks = 0; ks < 8; ++ks) {
      bf16x8 bfv = *(const bf16x8*)(S + l16 * SLD + ks * 32 + quad * 8);
      int g = ks * 4 + quad;
      #pragma unroll
      for (int tt = 0; tt < 4; ++tt) {
        bf16x8 af = *(const bf16x8*)(NTWs + (tt * 16 + l16) * 256 + ((g ^ xk) << 3));
        uac[tt] = MFMA(af, bfv, uac[tt]);
      }
    }
    #pragma unroll
    for (int tt = 0; tt < 4; ++tt)
      #pragma unroll
      for (int r = 0; r < 4; ++r)
        U[l16 * ULD + tt * 16 + quad * 4 + r] = f2bf(uac[tt][r]);

    // --- KdT half B load (latency hidden under o-phase) ---
    bf16x8 kdB[2][2][4];
    #pragma unroll
    for (int g2 = 0; g2 < 2; ++g2)
      #pragma unroll
      for (int ks = 0; ks < 2; ++ks)
        #pragma unroll
        for (int dt = 0; dt < 4; ++dt)
          kdB[g2][ks][dt] = *(const bf16x8*)(kdt + (((g2 + 2) * 4 + dt) * 16 + l16) * 64 + ks * 32 + quad * 8);

    // --- o = Qg @ S0 + M @ u (odd interleaved rows) ---
    f32x4 oac[2];
    #pragma unroll
    for (int tt = 0; tt < 2; ++tt) oac[tt] = zz;
    #pragma unroll
    for (int ks = 0; ks < 8; ++ks) {
      bf16x8 bfv = *(const bf16x8*)(S + l16 * SLD + ks * 32 + quad * 8);
      int g = ks * 4 + quad;
      #pragma unroll
      for (int tt = 0; tt < 2; ++tt) {
        bf16x8 af = *(const bf16x8*)(Qgs + (tt * 16 + l16) * 256 + ((g ^ xk) << 3));
        oac[tt] = MFMA(af, bfv, oac[tt]);
      }
    }
    #pragma unroll
    for (int ks = 0; ks < 2; ++ks) {
      bf16x8 bfv = *(const bf16x8*)(U + l16 * ULD + ks * 32 + quad * 8);
      #pragma unroll
      for (int tt = 0; tt < 2; ++tt)
        oac[tt] = MFMA(mmr[ks][tt], bfv, oac[tt]);
    }
    #pragma unroll
    for (int tt = 0; tt < 2; ++tt)
      #pragma unroll
      for (int r = 0; r < 4; ++r) {
        int th = tt * 16 + quad * 4 + r;
        int i = c * 32 + th;
        O[((size_t)(b * 1024 + i) * 6 + h) * 512 + vbase + l16] = f2bf(oac[tt][r]);
      }

    // --- S1 = dc * S0 + KdT @ u ---
    #pragma unroll
    for (int g2 = 0; g2 < 4; ++g2) {
      f32x4 sac[4];
      #pragma unroll
      for (int dt = 0; dt < 4; ++dt)
        #pragma unroll
        for (int r = 0; r < 4; ++r)
          sac[dt][r] = dc * bf2f(S[l16 * SLD + (g2 * 4 + dt) * 16 + quad * 4 + r]);
      #pragma unroll
      for (int ks = 0; ks < 2; ++ks) {
        bf16x8 bfv = *(const bf16x8*)(U + l16 * ULD + ks * 32 + quad * 8);
        #pragma unroll
        for (int dt = 0; dt < 4; ++dt) {
          bf16x8 af = (g2 < 2) ? kdA[g2][ks][dt] : kdB[g2 - 2][ks][dt];
          sac[dt] = MFMA(af, bfv, sac[dt]);
        }
      }
      #pragma unroll
      for (int dt = 0; dt < 4; ++dt)
        #pragma unroll
        for (int r = 0; r < 4; ++r)
          S[l16 * SLD + (g2 * 4 + dt) * 16 + quad * 4 + r] = f2bf(sac[dt][r]);
    }
  }
}

// ---------------------------------------------------------------------------
// RMS-norm over DV per (b,t,h), times silu(gate). grid (2048, 6).
__global__ __launch_bounds__(256) void rms_gate(
    const short* __restrict__ O, const short* __restrict__ P,
    const float* __restrict__ onw, short* __restrict__ OutPre)
{
  __shared__ float red[256];
  int tid = threadIdx.x, h = blockIdx.y, row = blockIdx.x;
  size_t base = ((size_t)row * 6 + h) * 512;
  float a = bf2f(O[base + tid]), b2 = bf2f(O[base + 256 + tid]);
  red[tid] = a * a + b2 * b2;
  __syncthreads();
  for (int s = 128; s > 0; s >>= 1) {
    if (tid < s) red[tid] += red[tid + s];
    __syncthreads();
  }
  float r = rsqrtf(red[0] * (1.f / 512.f) + 1e-5f);
  #pragma unroll
  for (int half = 0; half < 2; ++half) {
    int col = tid + half * 256;
    float ov = half ? b2 : a;
    float g = bf2f(P[(size_t)row * PJ_N + 10752 + h * 512 + col]);
    float sg = g / (1.f + expf(-g));
    OutPre[(size_t)row * 3072 + h * 512 + col] = f2bf(ov * r * onw[col] * sg);
  }
}

// ---------------------------------------------------------------------------
extern "C" void kernel_launch(void* const* d_in, const int* in_sizes, int n_in,
                              void* d_out, int out_size, void* d_ws, size_t ws_size,
                              hipStream_t stream) {
  const float* x        = (const float*)d_in[0];
  const float* q_w      = (const float*)d_in[1];
  const float* k_ws     = (const float*)d_in[2];
  const float* v_ws     = (const float*)d_in[3];
  const float* b_ws     = (const float*)d_in[4];
  const float* a_w      = (const float*)d_in[5];
  const float* g_w      = (const float*)d_in[6];
  const float* o_w      = (const float*)d_in[7];
  const float* q_conv_w = (const float*)d_in[8];
  const float* k_conv   = (const float*)d_in[9];
  const float* v_conv   = (const float*)d_in[10];
  const float* A_log    = (const float*)d_in[11];
  const float* dt_bias  = (const float*)d_in[12];
  const float* o_norm_w = (const float*)d_in[13];
  float* out = (float*)d_out;

  char* ws = (char*)d_ws;
  size_t off = 0;
  auto take = [&](size_t bytes) {
    size_t r = off;
    off += (bytes + 255) & ~(size_t)255;
    return r;
  };
  // Persistent buffers
  short* P  = (short*)(ws + take((size_t)NTOK * PJ_N * 2));   // live 3-8
  short* oT = (short*)(ws + take((size_t)2048 * 3072 * 2));   // live 2-9
  // xbf (step 3 only) reused for Mm (steps 6-7)
  size_t regX = take((size_t)NTOK * 2048 * 2);                // 8.39 MB
  short* xbf = (short*)(ws + regX);
  short* Mm  = (short*)(ws + regX);                           // 1.57 MB
  // Region A: WTall (steps 2-3) reused for NTW|Qg|KdT|TBV (steps 6-7)
  size_t regA = take((size_t)PJ_N * 2048 * 2);                // 56,623,104 B
  short* WTall = (short*)(ws + regA);
  short* NTW = (short*)(ws + regA);
  short* Qg  = NTW + (size_t)384 * 16384;
  short* KdT = Qg  + (size_t)384 * 8192;
  short* TBV = KdT + (size_t)384 * 16384;   // ends exactly at regA + 56,623,104
  // Region B: conv outputs (steps 5-6) reused for O/OutPre (steps 7-9)
  size_t regB = take((size_t)44040192);                       // 44.0 MB
  short* Qc  = (short*)(ws + regB);
  short* K0c = Qc  + (size_t)NTOK * 1536;
  short* K1c = K0c + (size_t)NTOK * 1536;
  short* V0c = K1c + (size_t)NTOK * 1536;
  short* V1c = V0c + (size_t)NTOK * 3072;
  short* O      = (short*)(ws + regB);                        // 12.6 MB
  short* OutPre = O + (size_t)NTOK * 6 * 512;                 // 12.6 MB
  float* Beta0 = (float*)(ws + take((size_t)NTOK * 6 * 4));
  float* Beta1 = (float*)(ws + take((size_t)NTOK * 6 * 4));
  float* G     = (float*)(ws + take((size_t)NTOK * 6 * 4));
  float* dCp   = (float*)(ws + take((size_t)384 * 4));
  if (off > ws_size) return;  // ws too small: no-op (diagnosable, capture-safe)

  // 1) convert x to bf16
  cvt_bf16<<<dim3(NTOK * 2048 / 8 / 256), 256, 0, stream>>>(x, xbf, NTOK * 2048);

  // 2) weight transposes (fp32 -> bf16) into WTall [q|k0|k1|v0|v1|gate] and oT
  transpose_w<<<dim3(24), 256, 0, stream>>>(q_w, WTall, 2048, 1536);
  transpose_w<<<dim3(24), 256, 0, stream>>>(k_ws, WTall + (size_t)1536 * 2048, 2048, 1536);
  transpose_w<<<dim3(24), 256, 0, stream>>>(k_ws + (size_t)2048 * 1536, WTall + (size_t)3072 * 2048, 2048, 1536);
  transpose_w<<<dim3(48), 256, 0, stream>>>(v_ws, WTall + (size_t)4608 * 2048, 2048, 3072);
  transpose_w<<<dim3(48), 256, 0, stream>>>(v_ws + (size_t)2048 * 3072, WTall + (size_t)7680 * 2048, 2048, 3072);
  transpose_w<<<dim3(48), 256, 0, stream>>>(g_w, WTall + (size_t)10752 * 2048, 2048, 3072);
  transpose_w<<<dim3(32), 256, 0, stream>>>(o_w, oT, 3072, 2048);

  // 3) fused projection GEMM (XCD-aware 1-D grid, N padded 108->112 tiles)
  gemm_bt<false><<<dim3(16 * 112), 256, 0, stream>>>(
      xbf, WTall, P, NTOK, PJ_N, 2048);

  // 4) beta / g (fp32 inputs straight from d_in)
  proj_small<<<dim3(NTOK), 64, 0, stream>>>(x, b_ws, a_w, A_log, dt_bias, Beta0, Beta1, G);

  // 5) conv + silu (+ l2norm for q/k)
  conv_norm_qk<<<dim3(NTOK, 6), 256, 0, stream>>>(P, q_conv_w, Qc, 0, 0.0625f);
  conv_norm_qk<<<dim3(NTOK, 6), 256, 0, stream>>>(P, k_conv, K0c, 1536, 1.f);
  conv_norm_qk<<<dim3(NTOK, 6), 256, 0, stream>>>(P, k_conv + (size_t)1536 * 4, K1c, 3072, 1.f);
  conv_v<<<dim3(NTOK, 12), 256, 0, stream>>>(P, v_conv, V0c, 4608);
  conv_v<<<dim3(NTOK, 12), 256, 0, stream>>>(P, v_conv + (size_t)3072 * 4, V1c, 7680);

  // 6) chunk operand precompute (WY form)
  precompute_chunk<<<dim3(32, 6, 2), 256, 0, stream>>>(Qc, K0c, K1c, V0c, V1c,
      Beta0, Beta1, G, NTW, Qg, KdT, Mm, TBV, dCp);

  // 7) sequential chunk scan (384 single-wave blocks, LDS-staged operands)
  scan_kernel<<<dim3(384), 64, 0, stream>>>(NTW, Qg, KdT, Mm, TBV, dCp, O);

  // 8) rms-norm * silu(gate)
  rms_gate<<<dim3(NTOK, 6), 256, 0, stream>>>(O, P, o_norm_w, OutPre);

  // 9) output projection (fp32 out)
  gemm_bt<true><<<dim3(16 * 16), 256, 0, stream>>>(
      OutPre, oT, out, NTOK, 2048, 3072);
}